// Round 3
// baseline (1175.114 us; speedup 1.0000x reference)
//
#include <hip/hip_runtime.h>

#define BLK 256
#define SHIFT 9
#define BSZ 512              // node-ids per bucket
#define MAXB 256             // max buckets (scan width); requires N <= 131072
#define SRCBITS 17
#define SRCMASK ((1u << SRCBITS) - 1u)
#define TILE 4096            // edges per binning block
#define AGG_THR 1024

// ===================== bucketed-scatter path =====================

// per-block LDS histogram of dst>>SHIFT, flushed to global bucketcnt
__global__ __launch_bounds__(BLK) void k_bcount(const int* __restrict__ dst, int E, int N,
                                                int* __restrict__ bucketcnt) {
    __shared__ int c[MAXB];
    for (int i = threadIdx.x; i < MAXB; i += BLK) c[i] = 0;
    __syncthreads();
    size_t ebase = (size_t)blockIdx.x * TILE;
#pragma unroll
    for (int q = 0; q < TILE / BLK; ++q) {
        size_t e = ebase + (size_t)q * BLK + threadIdx.x;
        if (e < (size_t)E) {
            int d = dst[e];
            if ((unsigned)d < (unsigned)N) atomicAdd(&c[d >> SHIFT], 1);
        }
    }
    __syncthreads();
    for (int i = threadIdx.x; i < MAXB; i += BLK) {
        int v = c[i];
        if (v) atomicAdd(&bucketcnt[i], v);
    }
}

// single block: exclusive scan of bucketcnt -> base[MAXB+1], cursor = base
__global__ __launch_bounds__(MAXB) void k_bscan(const int* __restrict__ bucketcnt,
                                                int* __restrict__ base,
                                                int* __restrict__ cursor) {
    __shared__ int s[MAXB];
    int t = threadIdx.x;
    int v = bucketcnt[t];
    s[t] = v;
    __syncthreads();
    for (int off = 1; off < MAXB; off <<= 1) {
        int u = (t >= off) ? s[t - off] : 0;
        __syncthreads();
        s[t] += u;
        __syncthreads();
    }
    int excl = s[t] - v;
    base[t] = excl;
    cursor[t] = excl;
    if (t == MAXB - 1) base[MAXB] = s[t];
}

// block-level counting sort: edges -> binned[] packed u32 (src | dl<<SRCBITS),
// grouped by bucket with semi-coalesced writes.
__global__ __launch_bounds__(BLK) void k_binA(const int* __restrict__ src,
                                              const int* __restrict__ dst, int E, int N,
                                              int* __restrict__ cursor,
                                              unsigned* __restrict__ binned) {
    __shared__ int cnt[MAXB];
    __shared__ int excl[MAXB];
    __shared__ int gb[MAXB];
    __shared__ int sscan[MAXB];
    __shared__ unsigned sw[TILE];
    __shared__ unsigned char sbk[TILE];
    int t = threadIdx.x;
    for (int i = t; i < MAXB; i += BLK) cnt[i] = 0;
    __syncthreads();
    size_t ebase = (size_t)blockIdx.x * TILE;
    unsigned ww[TILE / BLK];
    int rr[TILE / BLK];
    int bb[TILE / BLK];
#pragma unroll
    for (int q = 0; q < TILE / BLK; ++q) {
        size_t e = ebase + (size_t)q * BLK + t;
        bb[q] = -1;
        if (e < (size_t)E) {
            int d = dst[e], s0 = src[e];
            if ((unsigned)d < (unsigned)N && (unsigned)s0 < (unsigned)N) {
                int b = d >> SHIFT;
                ww[q] = (unsigned)s0 | ((unsigned)(d & (BSZ - 1)) << SRCBITS);
                rr[q] = atomicAdd(&cnt[b], 1);
                bb[q] = b;
            }
        }
    }
    __syncthreads();
    int v = cnt[t];
    sscan[t] = v;
    __syncthreads();
    for (int off = 1; off < MAXB; off <<= 1) {
        int u = (t >= off) ? sscan[t - off] : 0;
        __syncthreads();
        sscan[t] += u;
        __syncthreads();
    }
    excl[t] = sscan[t] - v;
    if (v > 0) gb[t] = atomicAdd(&cursor[t], v);
    __syncthreads();
    int total = sscan[MAXB - 1];
#pragma unroll
    for (int q = 0; q < TILE / BLK; ++q) {
        if (bb[q] >= 0) {
            int p = excl[bb[q]] + rr[q];
            sw[p] = ww[q];
            sbk[p] = (unsigned char)bb[q];
        }
    }
    __syncthreads();
    for (int p = t; p < total; p += BLK) {
        int b = sbk[p];
        binned[(size_t)gb[b] + (p - excl[b])] = sw[p];
    }
}

// per-bucket in-degree histogram (from binned) -> dinv
__global__ __launch_bounds__(BLK) void k_dinvB(const unsigned* __restrict__ binned,
                                               const int* __restrict__ bse, int N,
                                               float* __restrict__ dinv) {
    __shared__ int h[BSZ];
    int b = blockIdx.x;
    for (int i = threadIdx.x; i < BSZ; i += BLK) h[i] = 0;
    __syncthreads();
    int begin = bse[b], end = bse[b + 1];
    for (int k = begin + threadIdx.x; k < end; k += BLK) {
        unsigned w = binned[k];
        atomicAdd(&h[w >> SRCBITS], 1);
    }
    __syncthreads();
    int gb = b << SHIFT;
    for (int i = threadIdx.x; i < BSZ; i += BLK) {
        int n = gb + i;
        if (n < N) dinv[n] = rsqrtf((float)h[i] + 1.0f);
    }
}

// g1[i][:] = (x[i] @ W1) * dinv[i]   (32 -> 16)
__global__ __launch_bounds__(BLK) void k_transform1(const float* __restrict__ x,
                                                    const float* __restrict__ W1,
                                                    const float* __restrict__ dinv,
                                                    float* __restrict__ g1, int N) {
    __shared__ float sW[32 * 16];
    for (int t = threadIdx.x; t < 512; t += BLK) sW[t] = W1[t];
    __syncthreads();
    int i = blockIdx.x * BLK + threadIdx.x;
    if (i >= N) return;
    float xr[32];
    const float4* xp = (const float4*)(x + (size_t)i * 32);
#pragma unroll
    for (int q = 0; q < 8; ++q) {
        float4 v = xp[q];
        xr[4*q] = v.x; xr[4*q+1] = v.y; xr[4*q+2] = v.z; xr[4*q+3] = v.w;
    }
    float di = dinv[i];
    float o[16];
#pragma unroll
    for (int j = 0; j < 16; ++j) {
        float a = 0.f;
#pragma unroll
        for (int k = 0; k < 32; ++k) a += xr[k] * sW[k * 16 + j];
        o[j] = a * di;
    }
    float4* gp = (float4*)(g1 + (size_t)i * 16);
#pragma unroll
    for (int q = 0; q < 4; ++q)
        gp[q] = make_float4(o[4*q], o[4*q+1], o[4*q+2], o[4*q+3]);
}

// per-bucket layer-1 aggregation into LDS acc + epilogue + layer-2 transform.
__global__ __launch_bounds__(AGG_THR) void k_agg1f(const unsigned* __restrict__ binned,
                                                   const int* __restrict__ bse,
                                                   const float* __restrict__ g1,
                                                   const float* __restrict__ dinv,
                                                   const float* __restrict__ b1,
                                                   const float* __restrict__ W2,
                                                   float* __restrict__ g2, int N) {
    __shared__ float acc[BSZ * 16];  // 32 KiB
    __shared__ float sW[16 * 8];
    __shared__ float sb[16];
    int t = threadIdx.x;
    if (t < 128) sW[t] = W2[t];
    if (t < 16) sb[t] = b1[t];
    for (int i = t; i < BSZ * 16; i += AGG_THR) acc[i] = 0.f;
    __syncthreads();
    int b = blockIdx.x;
    int begin = bse[b], end = bse[b + 1];
    int f = t & 15;
    int slot = t >> 4;  // 0..63
    for (int k = begin + slot; k < end; k += AGG_THR / 16) {
        unsigned w = binned[k];
        int s = (int)(w & SRCMASK);
        int dl = (int)(w >> SRCBITS);
        atomicAdd(&acc[dl * 16 + f], g1[(size_t)s * 16 + f]);
    }
    __syncthreads();
    if (t < BSZ) {
        int n = (b << SHIFT) + t;
        if (n < N) {
            float di = dinv[n];
            const float4* gp = (const float4*)(g1 + (size_t)n * 16);
            float h[16];
#pragma unroll
            for (int q = 0; q < 4; ++q) {
                float4 gv = gp[q];
                h[4*q+0] = fmaxf((acc[t*16+4*q+0] + gv.x) * di + sb[4*q+0], 0.f);
                h[4*q+1] = fmaxf((acc[t*16+4*q+1] + gv.y) * di + sb[4*q+1], 0.f);
                h[4*q+2] = fmaxf((acc[t*16+4*q+2] + gv.z) * di + sb[4*q+2], 0.f);
                h[4*q+3] = fmaxf((acc[t*16+4*q+3] + gv.w) * di + sb[4*q+3], 0.f);
            }
            float o[8];
#pragma unroll
            for (int j = 0; j < 8; ++j) {
                float a = 0.f;
#pragma unroll
                for (int k = 0; k < 16; ++k) a += h[k] * sW[k * 8 + j];
                o[j] = a * di;
            }
            float4* op = (float4*)(g2 + (size_t)n * 8);
            op[0] = make_float4(o[0], o[1], o[2], o[3]);
            op[1] = make_float4(o[4], o[5], o[6], o[7]);
        }
    }
}

// per-bucket layer-2 aggregation + epilogue + final fc -> out
__global__ __launch_bounds__(AGG_THR) void k_agg2f(const unsigned* __restrict__ binned,
                                                   const int* __restrict__ bse,
                                                   const float* __restrict__ g2,
                                                   const float* __restrict__ dinv,
                                                   const float* __restrict__ b2,
                                                   const float* __restrict__ Wfc,
                                                   const float* __restrict__ bfc,
                                                   float* __restrict__ out, int N) {
    __shared__ float acc[BSZ * 8];  // 16 KiB
    __shared__ float sW[8 * 4];
    __shared__ float sb2[8];
    __shared__ float sbf[4];
    int t = threadIdx.x;
    if (t < 32) sW[t] = Wfc[t];
    if (t < 8) sb2[t] = b2[t];
    if (t < 4) sbf[t] = bfc[t];
    for (int i = t; i < BSZ * 8; i += AGG_THR) acc[i] = 0.f;
    __syncthreads();
    int b = blockIdx.x;
    int begin = bse[b], end = bse[b + 1];
    int f = t & 7;
    int slot = t >> 3;  // 0..127
    for (int k = begin + slot; k < end; k += AGG_THR / 8) {
        unsigned w = binned[k];
        int s = (int)(w & SRCMASK);
        int dl = (int)(w >> SRCBITS);
        atomicAdd(&acc[dl * 8 + f], g2[(size_t)s * 8 + f]);
    }
    __syncthreads();
    if (t < BSZ) {
        int n = (b << SHIFT) + t;
        if (n < N) {
            float di = dinv[n];
            const float4* gp = (const float4*)(g2 + (size_t)n * 8);
            float h[8];
#pragma unroll
            for (int q = 0; q < 2; ++q) {
                float4 gv = gp[q];
                h[4*q+0] = fmaxf((acc[t*8+4*q+0] + gv.x) * di + sb2[4*q+0], 0.f);
                h[4*q+1] = fmaxf((acc[t*8+4*q+1] + gv.y) * di + sb2[4*q+1], 0.f);
                h[4*q+2] = fmaxf((acc[t*8+4*q+2] + gv.z) * di + sb2[4*q+2], 0.f);
                h[4*q+3] = fmaxf((acc[t*8+4*q+3] + gv.w) * di + sb2[4*q+3], 0.f);
            }
            float o[4];
#pragma unroll
            for (int k = 0; k < 4; ++k) {
                float a = sbf[k];
#pragma unroll
                for (int j = 0; j < 8; ++j) a += h[j] * sW[j * 4 + k];
                o[k] = a;
            }
            ((float4*)(out + (size_t)n * 4))[0] = make_float4(o[0], o[1], o[2], o[3]);
        }
    }
}

// ===================== fallback (round-1 atomic path) =====================

__global__ __launch_bounds__(BLK) void k_count(const int* __restrict__ dst, int E, int N,
                                               float* __restrict__ cnt) {
    int i = blockIdx.x * BLK + threadIdx.x;
    if (i < E) {
        int d = dst[i];
        if ((unsigned)d < (unsigned)N) atomicAdd(&cnt[d], 1.0f);
    }
}
__global__ __launch_bounds__(BLK) void k_dinv_f(float* __restrict__ cnt, int N) {
    int i = blockIdx.x * BLK + threadIdx.x;
    if (i < N) cnt[i] = rsqrtf(cnt[i] + 1.0f);
}
template <int F>
__global__ __launch_bounds__(BLK) void k_edge_agg(const int* __restrict__ src,
                                                  const int* __restrict__ dst,
                                                  int E, int N,
                                                  const float* __restrict__ g,
                                                  float* __restrict__ agg) {
    size_t t = (size_t)blockIdx.x * BLK + threadIdx.x;
    int e = (int)(t / F);
    int f = (int)(t & (F - 1));
    if (e >= E) return;
    int s = src[e], d = dst[e];
    if ((unsigned)s >= (unsigned)N || (unsigned)d >= (unsigned)N) return;
    atomicAdd(&agg[(size_t)d * F + f], g[(size_t)s * F + f]);
}
__global__ __launch_bounds__(BLK) void k_node1(const float* __restrict__ g1,
                                               const float* __restrict__ agg1,
                                               const float* __restrict__ dinv,
                                               const float* __restrict__ b1,
                                               const float* __restrict__ W2,
                                               float* __restrict__ g2, int N) {
    __shared__ float sW[16 * 8];
    __shared__ float sb[16];
    for (int t = threadIdx.x; t < 128; t += BLK) sW[t] = W2[t];
    if (threadIdx.x < 16) sb[threadIdx.x] = b1[threadIdx.x];
    __syncthreads();
    int i = blockIdx.x * BLK + threadIdx.x;
    if (i >= N) return;
    float di = dinv[i];
    const float4* gp = (const float4*)(g1 + (size_t)i * 16);
    const float4* ap = (const float4*)(agg1 + (size_t)i * 16);
    float h[16];
#pragma unroll
    for (int q = 0; q < 4; ++q) {
        float4 gv = gp[q], av = ap[q];
        h[4*q+0] = fmaxf((av.x + gv.x) * di + sb[4*q+0], 0.f);
        h[4*q+1] = fmaxf((av.y + gv.y) * di + sb[4*q+1], 0.f);
        h[4*q+2] = fmaxf((av.z + gv.z) * di + sb[4*q+2], 0.f);
        h[4*q+3] = fmaxf((av.w + gv.w) * di + sb[4*q+3], 0.f);
    }
    float o[8];
#pragma unroll
    for (int j = 0; j < 8; ++j) {
        float a = 0.f;
#pragma unroll
        for (int k = 0; k < 16; ++k) a += h[k] * sW[k * 8 + j];
        o[j] = a * di;
    }
    float4* op = (float4*)(g2 + (size_t)i * 8);
    op[0] = make_float4(o[0], o[1], o[2], o[3]);
    op[1] = make_float4(o[4], o[5], o[6], o[7]);
}
__global__ __launch_bounds__(BLK) void k_node2(const float* __restrict__ g2,
                                               const float* __restrict__ agg2,
                                               const float* __restrict__ dinv,
                                               const float* __restrict__ b2,
                                               const float* __restrict__ Wfc,
                                               const float* __restrict__ bfc,
                                               float* __restrict__ out, int N) {
    __shared__ float sW[8 * 4];
    __shared__ float sb2[8];
    __shared__ float sbf[4];
    if (threadIdx.x < 32) sW[threadIdx.x] = Wfc[threadIdx.x];
    if (threadIdx.x < 8) sb2[threadIdx.x] = b2[threadIdx.x];
    if (threadIdx.x < 4) sbf[threadIdx.x] = bfc[threadIdx.x];
    __syncthreads();
    int i = blockIdx.x * BLK + threadIdx.x;
    if (i >= N) return;
    float di = dinv[i];
    const float4* gp = (const float4*)(g2 + (size_t)i * 8);
    const float4* ap = (const float4*)(agg2 + (size_t)i * 8);
    float h[8];
#pragma unroll
    for (int q = 0; q < 2; ++q) {
        float4 gv = gp[q], av = ap[q];
        h[4*q+0] = fmaxf((av.x + gv.x) * di + sb2[4*q+0], 0.f);
        h[4*q+1] = fmaxf((av.y + gv.y) * di + sb2[4*q+1], 0.f);
        h[4*q+2] = fmaxf((av.z + gv.z) * di + sb2[4*q+2], 0.f);
        h[4*q+3] = fmaxf((av.w + gv.w) * di + sb2[4*q+3], 0.f);
    }
    float o[4];
#pragma unroll
    for (int k = 0; k < 4; ++k) {
        float a = sbf[k];
#pragma unroll
        for (int j = 0; j < 8; ++j) a += h[j] * sW[j * 4 + k];
        o[k] = a;
    }
    ((float4*)(out + (size_t)i * 4))[0] = make_float4(o[0], o[1], o[2], o[3]);
}

// ===================== launch =====================

extern "C" void kernel_launch(void* const* d_in, const int* in_sizes, int n_in,
                              void* d_out, int out_size, void* d_ws, size_t ws_size,
                              hipStream_t stream) {
    const float* x   = (const float*)d_in[0];
    const int*   ei  = (const int*)d_in[1];
    const float* W1  = (const float*)d_in[2];
    const float* b1  = (const float*)d_in[3];
    const float* W2  = (const float*)d_in[4];
    const float* b2  = (const float*)d_in[5];
    const float* Wfc = (const float*)d_in[6];
    const float* bfc = (const float*)d_in[7];

    int N = in_sizes[0] / 32;
    int E = in_sizes[1] / 2;
    const int* src = ei;
    const int* dst = ei + (size_t)E;

    // bucketed-path workspace (words)
    size_t w_g1   = 0;                              // 16N f
    size_t w_g2   = w_g1 + (size_t)16 * N;          // 8N f
    size_t w_bin  = w_g2 + (size_t)8 * N;           // E u32
    size_t w_dinv = w_bin + (size_t)E;              // N f
    size_t w_bcnt = w_dinv + (size_t)N;             // MAXB i
    size_t w_base = w_bcnt + MAXB;                  // MAXB+1 i
    size_t w_cur  = w_base + MAXB + 1;              // MAXB i
    size_t need   = (w_cur + MAXB) * 4;

    bool fast = (ws_size >= need) && (N <= (1 << SRCBITS));

    if (fast) {
        float*    ws    = (float*)d_ws;
        float*    g1    = ws + w_g1;
        float*    g2    = ws + w_g2;
        unsigned* binned = (unsigned*)(ws + w_bin);
        float*    dinv  = ws + w_dinv;
        int*      bcnt  = (int*)(ws + w_bcnt);
        int*      base  = (int*)(ws + w_base);
        int*      cur   = (int*)(ws + w_cur);

        int nbuk = (N + BSZ - 1) >> SHIFT;
        int nbin = (E + TILE - 1) / TILE;

        hipMemsetAsync(bcnt, 0, MAXB * 4, stream);

        k_bcount<<<nbin, BLK, 0, stream>>>(dst, E, N, bcnt);
        k_bscan<<<1, MAXB, 0, stream>>>(bcnt, base, cur);
        k_binA<<<nbin, BLK, 0, stream>>>(src, dst, E, N, cur, binned);
        k_dinvB<<<nbuk, BLK, 0, stream>>>(binned, base, N, dinv);
        k_transform1<<<(N + BLK - 1) / BLK, BLK, 0, stream>>>(x, W1, dinv, g1, N);
        k_agg1f<<<nbuk, AGG_THR, 0, stream>>>(binned, base, g1, dinv, b1, W2, g2, N);
        k_agg2f<<<nbuk, AGG_THR, 0, stream>>>(binned, base, g2, dinv, b2, Wfc, bfc,
                                              (float*)d_out, N);
    } else {
        // round-1 atomic fallback
        float* ws   = (float*)d_ws;
        float* dinv = ws;                       // N
        float* g1   = dinv + (size_t)N;         // 16N
        float* agg1 = g1 + (size_t)16 * N;      // 16N
        float* g2   = agg1 + (size_t)16 * N;    // 8N
        float* agg2 = g2 + (size_t)8 * N;       // 8N

        hipMemsetAsync(dinv, 0, (size_t)N * 4, stream);
        hipMemsetAsync(agg1, 0, (size_t)16 * N * 4, stream);
        hipMemsetAsync(agg2, 0, (size_t)8 * N * 4, stream);

        k_count<<<(E + BLK - 1) / BLK, BLK, 0, stream>>>(dst, E, N, dinv);
        k_dinv_f<<<(N + BLK - 1) / BLK, BLK, 0, stream>>>(dinv, N);
        k_transform1<<<(N + BLK - 1) / BLK, BLK, 0, stream>>>(x, W1, dinv, g1, N);
        {
            size_t tot = (size_t)E * 16;
            k_edge_agg<16><<<(unsigned)((tot + BLK - 1) / BLK), BLK, 0, stream>>>(src, dst, E, N, g1, agg1);
        }
        k_node1<<<(N + BLK - 1) / BLK, BLK, 0, stream>>>(g1, agg1, dinv, b1, W2, g2, N);
        {
            size_t tot = (size_t)E * 8;
            k_edge_agg<8><<<(unsigned)((tot + BLK - 1) / BLK), BLK, 0, stream>>>(src, dst, E, N, g2, agg2);
        }
        k_node2<<<(N + BLK - 1) / BLK, BLK, 0, stream>>>(g2, agg2, dinv, b2, Wfc, bfc, (float*)d_out, N);
    }
}

// Round 4
// 1168.863 us; speedup vs baseline: 1.0053x; 1.0053x over previous
//
#include <hip/hip_runtime.h>
#include <hip/hip_fp16.h>

#define BLK 256
#define SHIFT 9
#define BSZ 512              // node-ids per bucket
#define MAXB 256             // max buckets; requires N <= 131072
#define SRCBITS 17
#define SRCMASK ((1u << SRCBITS) - 1u)
#define TILE 4096            // edges per binning block
#define CH 8192              // edges per aggregation chunk
#define NC 5                 // chunk-stride (grid.y); stride loop covers any count
#define AGT 1024             // aggregation block threads

// ===================== binning =====================

__global__ __launch_bounds__(BLK) void k_bcount(const int* __restrict__ dst, int E, int N,
                                                int* __restrict__ bucketcnt) {
    __shared__ int c[MAXB];
    for (int i = threadIdx.x; i < MAXB; i += BLK) c[i] = 0;
    __syncthreads();
    size_t ebase = (size_t)blockIdx.x * TILE;
#pragma unroll
    for (int q = 0; q < TILE / BLK; ++q) {
        size_t e = ebase + (size_t)q * BLK + threadIdx.x;
        if (e < (size_t)E) {
            int d = dst[e];
            if ((unsigned)d < (unsigned)N) atomicAdd(&c[d >> SHIFT], 1);
        }
    }
    __syncthreads();
    for (int i = threadIdx.x; i < MAXB; i += BLK) {
        int v = c[i];
        if (v) atomicAdd(&bucketcnt[i], v);
    }
}

__global__ __launch_bounds__(MAXB) void k_bscan(const int* __restrict__ bucketcnt,
                                                int* __restrict__ base,
                                                int* __restrict__ cursor) {
    __shared__ int s[MAXB];
    int t = threadIdx.x;
    int v = bucketcnt[t];
    s[t] = v;
    __syncthreads();
    for (int off = 1; off < MAXB; off <<= 1) {
        int u = (t >= off) ? s[t - off] : 0;
        __syncthreads();
        s[t] += u;
        __syncthreads();
    }
    int excl = s[t] - v;
    base[t] = excl;
    cursor[t] = excl;
    if (t == MAXB - 1) base[MAXB] = s[t];
}

__global__ __launch_bounds__(BLK) void k_binA(const int* __restrict__ src,
                                              const int* __restrict__ dst, int E, int N,
                                              int* __restrict__ cursor,
                                              unsigned* __restrict__ binned) {
    __shared__ int cnt[MAXB];
    __shared__ int excl[MAXB];
    __shared__ int gb[MAXB];
    __shared__ int sscan[MAXB];
    __shared__ unsigned sw[TILE];
    __shared__ unsigned char sbk[TILE];
    int t = threadIdx.x;
    for (int i = t; i < MAXB; i += BLK) cnt[i] = 0;
    __syncthreads();
    size_t ebase = (size_t)blockIdx.x * TILE;
    unsigned ww[TILE / BLK];
    int rr[TILE / BLK];
    int bb[TILE / BLK];
#pragma unroll
    for (int q = 0; q < TILE / BLK; ++q) {
        size_t e = ebase + (size_t)q * BLK + t;
        bb[q] = -1;
        if (e < (size_t)E) {
            int d = dst[e], s0 = src[e];
            if ((unsigned)d < (unsigned)N && (unsigned)s0 < (unsigned)N) {
                int b = d >> SHIFT;
                ww[q] = (unsigned)s0 | ((unsigned)(d & (BSZ - 1)) << SRCBITS);
                rr[q] = atomicAdd(&cnt[b], 1);
                bb[q] = b;
            }
        }
    }
    __syncthreads();
    int v = cnt[t];
    sscan[t] = v;
    __syncthreads();
    for (int off = 1; off < MAXB; off <<= 1) {
        int u = (t >= off) ? sscan[t - off] : 0;
        __syncthreads();
        sscan[t] += u;
        __syncthreads();
    }
    excl[t] = sscan[t] - v;
    if (v > 0) gb[t] = atomicAdd(&cursor[t], v);
    __syncthreads();
    int total = sscan[MAXB - 1];
#pragma unroll
    for (int q = 0; q < TILE / BLK; ++q) {
        if (bb[q] >= 0) {
            int p = excl[bb[q]] + rr[q];
            sw[p] = ww[q];
            sbk[p] = (unsigned char)bb[q];
        }
    }
    __syncthreads();
    for (int p = t; p < total; p += BLK) {
        int b = sbk[p];
        binned[(size_t)gb[b] + (p - excl[b])] = sw[p];
    }
}

__global__ __launch_bounds__(BLK) void k_dinvB(const unsigned* __restrict__ binned,
                                               const int* __restrict__ bse, int N,
                                               float* __restrict__ dinv) {
    __shared__ int h[BSZ];
    int b = blockIdx.x;
    for (int i = threadIdx.x; i < BSZ; i += BLK) h[i] = 0;
    __syncthreads();
    int begin = bse[b], end = bse[b + 1];
    for (int k = begin + threadIdx.x; k < end; k += BLK) {
        unsigned w = binned[k];
        atomicAdd(&h[w >> SRCBITS], 1);
    }
    __syncthreads();
    int gb = b << SHIFT;
    for (int i = threadIdx.x; i < BSZ; i += BLK) {
        int n = gb + i;
        if (n < N) dinv[n] = rsqrtf((float)h[i] + 1.0f);
    }
}

// ===================== transforms / epilogues =====================

union Pk8 { __half h[8]; uint4 u; };

// g1h[i][0..16) = half((x[i] @ W1) * dinv[i])   (32 -> 16), stride 16 halves
__global__ __launch_bounds__(BLK) void k_transform1h(const float* __restrict__ x,
                                                     const float* __restrict__ W1,
                                                     const float* __restrict__ dinv,
                                                     __half* __restrict__ g1h, int N) {
    __shared__ float sW[32 * 16];
    for (int t = threadIdx.x; t < 512; t += BLK) sW[t] = W1[t];
    __syncthreads();
    int i = blockIdx.x * BLK + threadIdx.x;
    if (i >= N) return;
    float xr[32];
    const float4* xp = (const float4*)(x + (size_t)i * 32);
#pragma unroll
    for (int q = 0; q < 8; ++q) {
        float4 v = xp[q];
        xr[4*q] = v.x; xr[4*q+1] = v.y; xr[4*q+2] = v.z; xr[4*q+3] = v.w;
    }
    float di = dinv[i];
    Pk8 p0, p1;
#pragma unroll
    for (int j = 0; j < 16; ++j) {
        float a = 0.f;
#pragma unroll
        for (int k = 0; k < 32; ++k) a += xr[k] * sW[k * 16 + j];
        if (j < 8) p0.h[j] = __float2half_rn(a * di);
        else       p1.h[j - 8] = __float2half_rn(a * di);
    }
    uint4* gp = (uint4*)(g1h + (size_t)i * 16);
    gp[0] = p0.u;
    gp[1] = p1.u;
}

// chunked edge-parallel aggregation: LDS accumulate + single global-atomic flush.
// g rows are 16-half strided; agg rows are 16-float strided (first F used).
template <int F>
__global__ __launch_bounds__(AGT) void k_aggE(const unsigned* __restrict__ binned,
                                              const int* __restrict__ base,
                                              const __half* __restrict__ g,
                                              float* __restrict__ agg, int N) {
    __shared__ float acc[BSZ * F];
    int b = blockIdx.x;
    int bb = base[b], be = base[b + 1];
    int w0 = bb + blockIdx.y * CH;
    if (w0 >= be) return;
    int t = threadIdx.x;
    for (int i = t; i < BSZ * F; i += AGT) acc[i] = 0.f;
    __syncthreads();
    const int SLOTS = AGT / F;
    int f = t & (F - 1);
    int slot = t / F;
    for (int cb = w0; cb < be; cb += NC * CH) {
        int ce = cb + CH; if (ce > be) ce = be;
        int k = cb + slot;
        for (; k + 3 * SLOTS < ce; k += 4 * SLOTS) {
            unsigned e0 = binned[k];
            unsigned e1 = binned[k + SLOTS];
            unsigned e2 = binned[k + 2 * SLOTS];
            unsigned e3 = binned[k + 3 * SLOTS];
            float v0 = __half2float(g[(size_t)(e0 & SRCMASK) * 16 + f]);
            float v1 = __half2float(g[(size_t)(e1 & SRCMASK) * 16 + f]);
            float v2 = __half2float(g[(size_t)(e2 & SRCMASK) * 16 + f]);
            float v3 = __half2float(g[(size_t)(e3 & SRCMASK) * 16 + f]);
            atomicAdd(&acc[(e0 >> SRCBITS) * F + f], v0);
            atomicAdd(&acc[(e1 >> SRCBITS) * F + f], v1);
            atomicAdd(&acc[(e2 >> SRCBITS) * F + f], v2);
            atomicAdd(&acc[(e3 >> SRCBITS) * F + f], v3);
        }
        for (; k < ce; k += SLOTS) {
            unsigned e0 = binned[k];
            atomicAdd(&acc[(e0 >> SRCBITS) * F + f],
                      __half2float(g[(size_t)(e0 & SRCMASK) * 16 + f]));
        }
    }
    __syncthreads();
    int gb = b << SHIFT;
    for (int i = t; i < BSZ * F; i += AGT) {
        float v = acc[i];
        int node = gb + i / F;
        if (node < N && v != 0.f)
            atomicAdd(&agg[(size_t)node * 16 + (i & (F - 1))], v);
    }
}

// layer-1 epilogue + layer-2 transform; writes g2h in place over g1h rows.
__global__ __launch_bounds__(BLK) void k_node1h(__half* __restrict__ g1h,
                                                const float* __restrict__ agg,
                                                const float* __restrict__ dinv,
                                                const float* __restrict__ b1,
                                                const float* __restrict__ W2, int N) {
    __shared__ float sW[16 * 8];
    __shared__ float sb[16];
    if (threadIdx.x < 128) sW[threadIdx.x] = W2[threadIdx.x];
    if (threadIdx.x < 16) sb[threadIdx.x] = b1[threadIdx.x];
    __syncthreads();
    int i = blockIdx.x * BLK + threadIdx.x;
    if (i >= N) return;
    float di = dinv[i];
    Pk8 s0, s1;
    const uint4* gp = (const uint4*)(g1h + (size_t)i * 16);
    s0.u = gp[0];
    s1.u = gp[1];
    const float4* ap = (const float4*)(agg + (size_t)i * 16);
    float h[16];
#pragma unroll
    for (int q = 0; q < 4; ++q) {
        float4 av = ap[q];
        float g0 = __half2float(q < 2 ? s0.h[4*q+0] : s1.h[4*q-8+0]);
        float g1v = __half2float(q < 2 ? s0.h[4*q+1] : s1.h[4*q-8+1]);
        float g2v = __half2float(q < 2 ? s0.h[4*q+2] : s1.h[4*q-8+2]);
        float g3 = __half2float(q < 2 ? s0.h[4*q+3] : s1.h[4*q-8+3]);
        h[4*q+0] = fmaxf((av.x + g0) * di + sb[4*q+0], 0.f);
        h[4*q+1] = fmaxf((av.y + g1v) * di + sb[4*q+1], 0.f);
        h[4*q+2] = fmaxf((av.z + g2v) * di + sb[4*q+2], 0.f);
        h[4*q+3] = fmaxf((av.w + g3) * di + sb[4*q+3], 0.f);
    }
    Pk8 o;
#pragma unroll
    for (int j = 0; j < 8; ++j) {
        float a = 0.f;
#pragma unroll
        for (int k = 0; k < 16; ++k) a += h[k] * sW[k * 8 + j];
        o.h[j] = __float2half_rn(a * di);
    }
    ((uint4*)(g1h + (size_t)i * 16))[0] = o.u;   // in-place: same thread's row
}

// layer-2 epilogue + final fc (8 -> 4) -> out
__global__ __launch_bounds__(BLK) void k_node2h(const __half* __restrict__ g2h,
                                                const float* __restrict__ agg,
                                                const float* __restrict__ dinv,
                                                const float* __restrict__ b2,
                                                const float* __restrict__ Wfc,
                                                const float* __restrict__ bfc,
                                                float* __restrict__ out, int N) {
    __shared__ float sW[8 * 4];
    __shared__ float sb2[8];
    __shared__ float sbf[4];
    if (threadIdx.x < 32) sW[threadIdx.x] = Wfc[threadIdx.x];
    if (threadIdx.x < 8) sb2[threadIdx.x] = b2[threadIdx.x];
    if (threadIdx.x < 4) sbf[threadIdx.x] = bfc[threadIdx.x];
    __syncthreads();
    int i = blockIdx.x * BLK + threadIdx.x;
    if (i >= N) return;
    float di = dinv[i];
    Pk8 s0;
    s0.u = ((const uint4*)(g2h + (size_t)i * 16))[0];
    const float4* ap = (const float4*)(agg + (size_t)i * 16);
    float h[8];
#pragma unroll
    for (int q = 0; q < 2; ++q) {
        float4 av = ap[q];
        h[4*q+0] = fmaxf((av.x + __half2float(s0.h[4*q+0])) * di + sb2[4*q+0], 0.f);
        h[4*q+1] = fmaxf((av.y + __half2float(s0.h[4*q+1])) * di + sb2[4*q+1], 0.f);
        h[4*q+2] = fmaxf((av.z + __half2float(s0.h[4*q+2])) * di + sb2[4*q+2], 0.f);
        h[4*q+3] = fmaxf((av.w + __half2float(s0.h[4*q+3])) * di + sb2[4*q+3], 0.f);
    }
    float o[4];
#pragma unroll
    for (int k = 0; k < 4; ++k) {
        float a = sbf[k];
#pragma unroll
        for (int j = 0; j < 8; ++j) a += h[j] * sW[j * 4 + k];
        o[k] = a;
    }
    ((float4*)(out + (size_t)i * 4))[0] = make_float4(o[0], o[1], o[2], o[3]);
}

// ===================== fallback (round-1 atomic path) =====================

__global__ __launch_bounds__(BLK) void k_count(const int* __restrict__ dst, int E, int N,
                                               float* __restrict__ cnt) {
    int i = blockIdx.x * BLK + threadIdx.x;
    if (i < E) {
        int d = dst[i];
        if ((unsigned)d < (unsigned)N) atomicAdd(&cnt[d], 1.0f);
    }
}
__global__ __launch_bounds__(BLK) void k_dinv_f(float* __restrict__ cnt, int N) {
    int i = blockIdx.x * BLK + threadIdx.x;
    if (i < N) cnt[i] = rsqrtf(cnt[i] + 1.0f);
}
__global__ __launch_bounds__(BLK) void k_transform1(const float* __restrict__ x,
                                                    const float* __restrict__ W1,
                                                    const float* __restrict__ dinv,
                                                    float* __restrict__ g1, int N) {
    __shared__ float sW[32 * 16];
    for (int t = threadIdx.x; t < 512; t += BLK) sW[t] = W1[t];
    __syncthreads();
    int i = blockIdx.x * BLK + threadIdx.x;
    if (i >= N) return;
    float xr[32];
    const float4* xp = (const float4*)(x + (size_t)i * 32);
#pragma unroll
    for (int q = 0; q < 8; ++q) {
        float4 v = xp[q];
        xr[4*q] = v.x; xr[4*q+1] = v.y; xr[4*q+2] = v.z; xr[4*q+3] = v.w;
    }
    float di = dinv[i];
    float o[16];
#pragma unroll
    for (int j = 0; j < 16; ++j) {
        float a = 0.f;
#pragma unroll
        for (int k = 0; k < 32; ++k) a += xr[k] * sW[k * 16 + j];
        o[j] = a * di;
    }
    float4* gp = (float4*)(g1 + (size_t)i * 16);
#pragma unroll
    for (int q = 0; q < 4; ++q)
        gp[q] = make_float4(o[4*q], o[4*q+1], o[4*q+2], o[4*q+3]);
}
template <int F>
__global__ __launch_bounds__(BLK) void k_edge_agg(const int* __restrict__ src,
                                                  const int* __restrict__ dst,
                                                  int E, int N,
                                                  const float* __restrict__ g,
                                                  float* __restrict__ agg) {
    size_t t = (size_t)blockIdx.x * BLK + threadIdx.x;
    int e = (int)(t / F);
    int f = (int)(t & (F - 1));
    if (e >= E) return;
    int s = src[e], d = dst[e];
    if ((unsigned)s >= (unsigned)N || (unsigned)d >= (unsigned)N) return;
    atomicAdd(&agg[(size_t)d * F + f], g[(size_t)s * F + f]);
}
__global__ __launch_bounds__(BLK) void k_node1(const float* __restrict__ g1,
                                               const float* __restrict__ agg1,
                                               const float* __restrict__ dinv,
                                               const float* __restrict__ b1,
                                               const float* __restrict__ W2,
                                               float* __restrict__ g2, int N) {
    __shared__ float sW[16 * 8];
    __shared__ float sb[16];
    for (int t = threadIdx.x; t < 128; t += BLK) sW[t] = W2[t];
    if (threadIdx.x < 16) sb[threadIdx.x] = b1[threadIdx.x];
    __syncthreads();
    int i = blockIdx.x * BLK + threadIdx.x;
    if (i >= N) return;
    float di = dinv[i];
    const float4* gp = (const float4*)(g1 + (size_t)i * 16);
    const float4* ap = (const float4*)(agg1 + (size_t)i * 16);
    float h[16];
#pragma unroll
    for (int q = 0; q < 4; ++q) {
        float4 gv = gp[q], av = ap[q];
        h[4*q+0] = fmaxf((av.x + gv.x) * di + sb[4*q+0], 0.f);
        h[4*q+1] = fmaxf((av.y + gv.y) * di + sb[4*q+1], 0.f);
        h[4*q+2] = fmaxf((av.z + gv.z) * di + sb[4*q+2], 0.f);
        h[4*q+3] = fmaxf((av.w + gv.w) * di + sb[4*q+3], 0.f);
    }
    float o[8];
#pragma unroll
    for (int j = 0; j < 8; ++j) {
        float a = 0.f;
#pragma unroll
        for (int k = 0; k < 16; ++k) a += h[k] * sW[k * 8 + j];
        o[j] = a * di;
    }
    float4* op = (float4*)(g2 + (size_t)i * 8);
    op[0] = make_float4(o[0], o[1], o[2], o[3]);
    op[1] = make_float4(o[4], o[5], o[6], o[7]);
}
__global__ __launch_bounds__(BLK) void k_node2(const float* __restrict__ g2,
                                               const float* __restrict__ agg2,
                                               const float* __restrict__ dinv,
                                               const float* __restrict__ b2,
                                               const float* __restrict__ Wfc,
                                               const float* __restrict__ bfc,
                                               float* __restrict__ out, int N) {
    __shared__ float sW[8 * 4];
    __shared__ float sb2[8];
    __shared__ float sbf[4];
    if (threadIdx.x < 32) sW[threadIdx.x] = Wfc[threadIdx.x];
    if (threadIdx.x < 8) sb2[threadIdx.x] = b2[threadIdx.x];
    if (threadIdx.x < 4) sbf[threadIdx.x] = bfc[threadIdx.x];
    __syncthreads();
    int i = blockIdx.x * BLK + threadIdx.x;
    if (i >= N) return;
    float di = dinv[i];
    const float4* gp = (const float4*)(g2 + (size_t)i * 8);
    const float4* ap = (const float4*)(agg2 + (size_t)i * 8);
    float h[8];
#pragma unroll
    for (int q = 0; q < 2; ++q) {
        float4 gv = gp[q], av = ap[q];
        h[4*q+0] = fmaxf((av.x + gv.x) * di + sb2[4*q+0], 0.f);
        h[4*q+1] = fmaxf((av.y + gv.y) * di + sb2[4*q+1], 0.f);
        h[4*q+2] = fmaxf((av.z + gv.z) * di + sb2[4*q+2], 0.f);
        h[4*q+3] = fmaxf((av.w + gv.w) * di + sb2[4*q+3], 0.f);
    }
    float o[4];
#pragma unroll
    for (int k = 0; k < 4; ++k) {
        float a = sbf[k];
#pragma unroll
        for (int j = 0; j < 8; ++j) a += h[j] * sW[j * 4 + k];
        o[k] = a;
    }
    ((float4*)(out + (size_t)i * 4))[0] = make_float4(o[0], o[1], o[2], o[3]);
}

// ===================== launch =====================

extern "C" void kernel_launch(void* const* d_in, const int* in_sizes, int n_in,
                              void* d_out, int out_size, void* d_ws, size_t ws_size,
                              hipStream_t stream) {
    const float* x   = (const float*)d_in[0];
    const int*   ei  = (const int*)d_in[1];
    const float* W1  = (const float*)d_in[2];
    const float* b1  = (const float*)d_in[3];
    const float* W2  = (const float*)d_in[4];
    const float* b2  = (const float*)d_in[5];
    const float* Wfc = (const float*)d_in[6];
    const float* bfc = (const float*)d_in[7];

    int N = in_sizes[0] / 32;
    int E = in_sizes[1] / 2;
    const int* src = ei;
    const int* dst = ei + (size_t)E;

    // fast-path workspace (words of 4B):
    size_t w_g1h  = 0;                              // 8N  (16 halves/node)
    size_t w_agg  = w_g1h + (size_t)8 * N;          // 16N f32
    size_t w_dinv = w_agg + (size_t)16 * N;         // N
    size_t w_bcnt = w_dinv + (size_t)N;             // 256
    size_t w_base = w_bcnt + MAXB;                  // 257
    size_t w_cur  = w_base + MAXB + 1;              // 256
    size_t w_bin  = (w_cur + MAXB + 3) & ~(size_t)3; // E
    size_t need   = (w_bin + (size_t)E) * 4;

    bool fast = (ws_size >= need) && (N <= (1 << SRCBITS));

    if (fast) {
        float*    ws     = (float*)d_ws;
        __half*   g1h    = (__half*)(ws + w_g1h);
        float*    agg    = ws + w_agg;
        float*    dinv   = ws + w_dinv;
        int*      bcnt   = (int*)(ws + w_bcnt);
        int*      base   = (int*)(ws + w_base);
        int*      cur    = (int*)(ws + w_cur);
        unsigned* binned = (unsigned*)(ws + w_bin);

        int nbuk = (N + BSZ - 1) >> SHIFT;
        int nbin = (E + TILE - 1) / TILE;
        int nnode = (N + BLK - 1) / BLK;

        hipMemsetAsync(bcnt, 0, MAXB * 4, stream);
        hipMemsetAsync(agg, 0, (size_t)16 * N * 4, stream);

        k_bcount<<<nbin, BLK, 0, stream>>>(dst, E, N, bcnt);
        k_bscan<<<1, MAXB, 0, stream>>>(bcnt, base, cur);
        k_binA<<<nbin, BLK, 0, stream>>>(src, dst, E, N, cur, binned);
        k_dinvB<<<nbuk, BLK, 0, stream>>>(binned, base, N, dinv);
        k_transform1h<<<nnode, BLK, 0, stream>>>(x, W1, dinv, g1h, N);

        k_aggE<16><<<dim3(nbuk, NC), AGT, 0, stream>>>(binned, base, g1h, agg, N);
        k_node1h<<<nnode, BLK, 0, stream>>>(g1h, agg, dinv, b1, W2, N);

        hipMemsetAsync(agg, 0, (size_t)16 * N * 4, stream);
        k_aggE<8><<<dim3(nbuk, NC), AGT, 0, stream>>>(binned, base, g1h, agg, N);
        k_node2h<<<nnode, BLK, 0, stream>>>(g1h, agg, dinv, b2, Wfc, bfc, (float*)d_out, N);
    } else {
        // round-1 atomic fallback
        float* ws   = (float*)d_ws;
        float* dinv = ws;                       // N
        float* g1   = dinv + (size_t)N;         // 16N
        float* agg1 = g1 + (size_t)16 * N;      // 16N
        float* g2   = agg1 + (size_t)16 * N;    // 8N
        float* agg2 = g2 + (size_t)8 * N;       // 8N

        hipMemsetAsync(dinv, 0, (size_t)N * 4, stream);
        hipMemsetAsync(agg1, 0, (size_t)16 * N * 4, stream);
        hipMemsetAsync(agg2, 0, (size_t)8 * N * 4, stream);

        k_count<<<(E + BLK - 1) / BLK, BLK, 0, stream>>>(dst, E, N, dinv);
        k_dinv_f<<<(N + BLK - 1) / BLK, BLK, 0, stream>>>(dinv, N);
        k_transform1<<<(N + BLK - 1) / BLK, BLK, 0, stream>>>(x, W1, dinv, g1, N);
        {
            size_t tot = (size_t)E * 16;
            k_edge_agg<16><<<(unsigned)((tot + BLK - 1) / BLK), BLK, 0, stream>>>(src, dst, E, N, g1, agg1);
        }
        k_node1<<<(N + BLK - 1) / BLK, BLK, 0, stream>>>(g1, agg1, dinv, b1, W2, g2, N);
        {
            size_t tot = (size_t)E * 8;
            k_edge_agg<8><<<(unsigned)((tot + BLK - 1) / BLK), BLK, 0, stream>>>(src, dst, E, N, g2, agg2);
        }
        k_node2<<<(N + BLK - 1) / BLK, BLK, 0, stream>>>(g2, agg2, dinv, b2, Wfc, bfc, (float*)d_out, N);
    }
}

// Round 5
// 357.047 us; speedup vs baseline: 3.2912x; 3.2737x over previous
//
#include <hip/hip_runtime.h>
#include <hip/hip_fp16.h>

#define BLK 256
#define SHIFT 9
#define BSZ 512              // node-ids per bucket
#define MAXB 256             // max buckets; requires N <= 131072
#define SRCBITS 17
#define SRCMASK ((1u << SRCBITS) - 1u)
#define TILE 4096            // edges per binning block
#define CHS 8192             // edges per csr-build chunk
#define NCC 5                // chunk-stride (grid.y)

// ===================== binning (proven r4) =====================

__global__ __launch_bounds__(BLK) void k_bcount(const int* __restrict__ dst, int E, int N,
                                                int* __restrict__ bucketcnt) {
    __shared__ int c[MAXB];
    for (int i = threadIdx.x; i < MAXB; i += BLK) c[i] = 0;
    __syncthreads();
    size_t ebase = (size_t)blockIdx.x * TILE;
#pragma unroll
    for (int q = 0; q < TILE / BLK; ++q) {
        size_t e = ebase + (size_t)q * BLK + threadIdx.x;
        if (e < (size_t)E) {
            int d = dst[e];
            if ((unsigned)d < (unsigned)N) atomicAdd(&c[d >> SHIFT], 1);
        }
    }
    __syncthreads();
    for (int i = threadIdx.x; i < MAXB; i += BLK) {
        int v = c[i];
        if (v) atomicAdd(&bucketcnt[i], v);
    }
}

__global__ __launch_bounds__(MAXB) void k_bscan(const int* __restrict__ bucketcnt,
                                                int* __restrict__ base,
                                                int* __restrict__ cursor) {
    __shared__ int s[MAXB];
    int t = threadIdx.x;
    int v = bucketcnt[t];
    s[t] = v;
    __syncthreads();
    for (int off = 1; off < MAXB; off <<= 1) {
        int u = (t >= off) ? s[t - off] : 0;
        __syncthreads();
        s[t] += u;
        __syncthreads();
    }
    int excl = s[t] - v;
    base[t] = excl;
    cursor[t] = excl;
    if (t == MAXB - 1) base[MAXB] = s[t];
}

__global__ __launch_bounds__(BLK) void k_binA(const int* __restrict__ src,
                                              const int* __restrict__ dst, int E, int N,
                                              int* __restrict__ cursor,
                                              unsigned* __restrict__ binned) {
    __shared__ int cnt[MAXB];
    __shared__ int excl[MAXB];
    __shared__ int gb[MAXB];
    __shared__ int sscan[MAXB];
    __shared__ unsigned sw[TILE];
    __shared__ unsigned char sbk[TILE];
    int t = threadIdx.x;
    for (int i = t; i < MAXB; i += BLK) cnt[i] = 0;
    __syncthreads();
    size_t ebase = (size_t)blockIdx.x * TILE;
    unsigned ww[TILE / BLK];
    int rr[TILE / BLK];
    int bb[TILE / BLK];
#pragma unroll
    for (int q = 0; q < TILE / BLK; ++q) {
        size_t e = ebase + (size_t)q * BLK + t;
        bb[q] = -1;
        if (e < (size_t)E) {
            int d = dst[e], s0 = src[e];
            if ((unsigned)d < (unsigned)N && (unsigned)s0 < (unsigned)N) {
                int b = d >> SHIFT;
                ww[q] = (unsigned)s0 | ((unsigned)(d & (BSZ - 1)) << SRCBITS);
                rr[q] = atomicAdd(&cnt[b], 1);
                bb[q] = b;
            }
        }
    }
    __syncthreads();
    int v = cnt[t];
    sscan[t] = v;
    __syncthreads();
    for (int off = 1; off < MAXB; off <<= 1) {
        int u = (t >= off) ? sscan[t - off] : 0;
        __syncthreads();
        sscan[t] += u;
        __syncthreads();
    }
    excl[t] = sscan[t] - v;
    if (v > 0) gb[t] = atomicAdd(&cursor[t], v);
    __syncthreads();
    int total = sscan[MAXB - 1];
#pragma unroll
    for (int q = 0; q < TILE / BLK; ++q) {
        if (bb[q] >= 0) {
            int p = excl[bb[q]] + rr[q];
            sw[p] = ww[q];
            sbk[p] = (unsigned char)bb[q];
        }
    }
    __syncthreads();
    for (int p = t; p < total; p += BLK) {
        int b = sbk[p];
        binned[(size_t)gb[b] + (p - excl[b])] = sw[p];
    }
}

// ===================== per-bucket dinv + csr offsets =====================

// one 512-thread block per bucket: hist -> scan -> rp/cursor/dinv (no global scan)
__global__ __launch_bounds__(BSZ) void k_dinvB2(const unsigned* __restrict__ binned,
                                                const int* __restrict__ base, int N,
                                                float* __restrict__ dinv,
                                                int* __restrict__ rp,
                                                int* __restrict__ curN) {
    __shared__ int h[BSZ];
    __shared__ int sc[BSZ];
    int b = blockIdx.x;
    int t = threadIdx.x;
    h[t] = 0;
    __syncthreads();
    int bb = base[b], be = base[b + 1];
    for (int k = bb + t; k < be; k += BSZ) atomicAdd(&h[binned[k] >> SRCBITS], 1);
    __syncthreads();
    int v = h[t];
    sc[t] = v;
    __syncthreads();
    for (int off = 1; off < BSZ; off <<= 1) {
        int u = (t >= off) ? sc[t - off] : 0;
        __syncthreads();
        sc[t] += u;
        __syncthreads();
    }
    int excl = sc[t] - v;
    int gnode = (b << SHIFT) + t;
    if (gnode < N) {
        rp[gnode] = bb + excl;
        curN[gnode] = bb + excl;
        dinv[gnode] = rsqrtf((float)v + 1.0f);
    }
    if (t == BSZ - 1) {
        int endn = (b << SHIFT) + BSZ;
        if (endn > N) endn = N;
        rp[endn] = bb + sc[t];  // == base[b+1] for dense buckets; benign dup write
    }
}

// chunked exact csr build: rank via LDS int atomics, place via per-chunk cursors
__global__ __launch_bounds__(1024) void k_csr(const unsigned* __restrict__ binned,
                                              const int* __restrict__ base,
                                              int* __restrict__ curN,
                                              unsigned* __restrict__ csr) {
    __shared__ unsigned val[CHS];
    __shared__ unsigned short rnk[CHS];
    __shared__ int cnt[BSZ];
    __shared__ int nb[BSZ];
    int b = blockIdx.x;
    int bb = base[b], be = base[b + 1];
    int gb = b << SHIFT;
    int t = threadIdx.x;
    for (int cb = bb + blockIdx.y * CHS; cb < be; cb += NCC * CHS) {
        int ce = cb + CHS; if (ce > be) ce = be;
        int n = ce - cb;
        for (int i = t; i < BSZ; i += 1024) cnt[i] = 0;
        __syncthreads();
        for (int i = t; i < n; i += 1024) {
            unsigned v = binned[cb + i];
            val[i] = v;
            rnk[i] = (unsigned short)atomicAdd(&cnt[v >> SRCBITS], 1);
        }
        __syncthreads();
        for (int i = t; i < BSZ; i += 1024) {
            int c = cnt[i];
            if (c > 0) nb[i] = atomicAdd(&curN[gb + i], c);
        }
        __syncthreads();
        for (int i = t; i < n; i += 1024) {
            unsigned v = val[i];
            csr[nb[v >> SRCBITS] + rnk[i]] = v & SRCMASK;
        }
        __syncthreads();
    }
}

// ===================== transform =====================

union Pk8 { __half h[8]; uint4 u; };

// g1h[i][0..16) = half((x[i] @ W1) * dinv[i])   (32 -> 16)
__global__ __launch_bounds__(BLK) void k_transform1h(const float* __restrict__ x,
                                                     const float* __restrict__ W1,
                                                     const float* __restrict__ dinv,
                                                     __half* __restrict__ g1h, int N) {
    __shared__ float sW[32 * 16];
    for (int t = threadIdx.x; t < 512; t += BLK) sW[t] = W1[t];
    __syncthreads();
    int i = blockIdx.x * BLK + threadIdx.x;
    if (i >= N) return;
    float xr[32];
    const float4* xp = (const float4*)(x + (size_t)i * 32);
#pragma unroll
    for (int q = 0; q < 8; ++q) {
        float4 v = xp[q];
        xr[4*q] = v.x; xr[4*q+1] = v.y; xr[4*q+2] = v.z; xr[4*q+3] = v.w;
    }
    float di = dinv[i];
    Pk8 p0, p1;
#pragma unroll
    for (int j = 0; j < 16; ++j) {
        float a = 0.f;
#pragma unroll
        for (int k = 0; k < 32; ++k) a += xr[k] * sW[k * 16 + j];
        if (j < 8) p0.h[j] = __float2half_rn(a * di);
        else       p1.h[j - 8] = __float2half_rn(a * di);
    }
    uint4* gp = (uint4*)(g1h + (size_t)i * 16);
    gp[0] = p0.u;
    gp[1] = p1.u;
}

// ===================== register-acc aggregation (r2-proven + unroll) =====================

// wave per node: 4 edge-slots x 16 f; acc in registers; shfl reduce; fused
// epilogue (bias+relu+dinv) + 16->8 transform + prescale -> g2 (f32)
__global__ __launch_bounds__(BLK) void k_agg1(const int* __restrict__ rp,
                                              const unsigned* __restrict__ csr,
                                              const __half* __restrict__ g1h,
                                              const float* __restrict__ dinv,
                                              const float* __restrict__ b1,
                                              const float* __restrict__ W2,
                                              float* __restrict__ g2, int N) {
    __shared__ float sW[16 * 8];
    __shared__ float sb[16];
    if (threadIdx.x < 128) sW[threadIdx.x] = W2[threadIdx.x];
    if (threadIdx.x < 16) sb[threadIdx.x] = b1[threadIdx.x];
    __syncthreads();
    int wid = blockIdx.x * (BLK / 64) + (threadIdx.x >> 6);
    if (wid >= N) return;  // wave-uniform
    int lane = threadIdx.x & 63;
    int f = lane & 15;
    int slot = lane >> 4;  // 0..3
    int base_ = rp[wid], end = rp[wid + 1];
    float acc = 0.f;
    int k = base_ + slot;
    for (; k + 4 < end; k += 8) {
        unsigned s0 = csr[k], s1 = csr[k + 4];
        acc += __half2float(g1h[(size_t)s0 * 16 + f])
             + __half2float(g1h[(size_t)s1 * 16 + f]);
    }
    if (k < end) acc += __half2float(g1h[(size_t)csr[k] * 16 + f]);
    acc += __shfl_xor(acc, 16);
    acc += __shfl_xor(acc, 32);
    float di = dinv[wid];
    float self = __half2float(g1h[(size_t)wid * 16 + f]);
    float h = fmaxf((acc + self) * di + sb[f], 0.f);  // h1[f], dup x4
    int gbase = lane & ~15;
    int o = lane & 7;
    float a = 0.f;
#pragma unroll
    for (int kk = 0; kk < 16; ++kk) a += __shfl(h, gbase + kk) * sW[kk * 8 + o];
    if (lane < 8) g2[(size_t)wid * 8 + lane] = a * di;
}

// wave per node: 8 edge-slots x 8 f; fused epilogue + final fc (8->4)+bias -> out
__global__ __launch_bounds__(BLK) void k_agg2(const int* __restrict__ rp,
                                              const unsigned* __restrict__ csr,
                                              const float* __restrict__ g2,
                                              const float* __restrict__ dinv,
                                              const float* __restrict__ b2,
                                              const float* __restrict__ Wfc,
                                              const float* __restrict__ bfc,
                                              float* __restrict__ out, int N) {
    __shared__ float sW[8 * 4];
    __shared__ float sb2[8];
    __shared__ float sbf[4];
    if (threadIdx.x < 32) sW[threadIdx.x] = Wfc[threadIdx.x];
    if (threadIdx.x < 8) sb2[threadIdx.x] = b2[threadIdx.x];
    if (threadIdx.x < 4) sbf[threadIdx.x] = bfc[threadIdx.x];
    __syncthreads();
    int wid = blockIdx.x * (BLK / 64) + (threadIdx.x >> 6);
    if (wid >= N) return;
    int lane = threadIdx.x & 63;
    int f = lane & 7;
    int slot = lane >> 3;  // 0..7
    int base_ = rp[wid], end = rp[wid + 1];
    float acc = 0.f;
    int k = base_ + slot;
    for (; k + 8 < end; k += 16) {
        unsigned s0 = csr[k], s1 = csr[k + 8];
        acc += g2[(size_t)s0 * 8 + f] + g2[(size_t)s1 * 8 + f];
    }
    if (k < end) acc += g2[(size_t)csr[k] * 8 + f];
    acc += __shfl_xor(acc, 8);
    acc += __shfl_xor(acc, 16);
    acc += __shfl_xor(acc, 32);
    float di = dinv[wid];
    float self = g2[(size_t)wid * 8 + f];
    float h = fmaxf((acc + self) * di + sb2[f], 0.f);  // h2[f], dup x8
    int gbase = lane & ~7;
    int o = lane & 3;
    float a = 0.f;
#pragma unroll
    for (int j = 0; j < 8; ++j) a += __shfl(h, gbase + j) * sW[j * 4 + o];
    if (lane < 4) out[(size_t)wid * 4 + lane] = a + sbf[lane];
}

// ===================== fallback (round-1 atomic path) =====================

__global__ __launch_bounds__(BLK) void k_count(const int* __restrict__ dst, int E, int N,
                                               float* __restrict__ cnt) {
    int i = blockIdx.x * BLK + threadIdx.x;
    if (i < E) {
        int d = dst[i];
        if ((unsigned)d < (unsigned)N) atomicAdd(&cnt[d], 1.0f);
    }
}
__global__ __launch_bounds__(BLK) void k_dinv_f(float* __restrict__ cnt, int N) {
    int i = blockIdx.x * BLK + threadIdx.x;
    if (i < N) cnt[i] = rsqrtf(cnt[i] + 1.0f);
}
__global__ __launch_bounds__(BLK) void k_transform1(const float* __restrict__ x,
                                                    const float* __restrict__ W1,
                                                    const float* __restrict__ dinv,
                                                    float* __restrict__ g1, int N) {
    __shared__ float sW[32 * 16];
    for (int t = threadIdx.x; t < 512; t += BLK) sW[t] = W1[t];
    __syncthreads();
    int i = blockIdx.x * BLK + threadIdx.x;
    if (i >= N) return;
    float xr[32];
    const float4* xp = (const float4*)(x + (size_t)i * 32);
#pragma unroll
    for (int q = 0; q < 8; ++q) {
        float4 v = xp[q];
        xr[4*q] = v.x; xr[4*q+1] = v.y; xr[4*q+2] = v.z; xr[4*q+3] = v.w;
    }
    float di = dinv[i];
    float o[16];
#pragma unroll
    for (int j = 0; j < 16; ++j) {
        float a = 0.f;
#pragma unroll
        for (int k = 0; k < 32; ++k) a += xr[k] * sW[k * 16 + j];
        o[j] = a * di;
    }
    float4* gp = (float4*)(g1 + (size_t)i * 16);
#pragma unroll
    for (int q = 0; q < 4; ++q)
        gp[q] = make_float4(o[4*q], o[4*q+1], o[4*q+2], o[4*q+3]);
}
template <int F>
__global__ __launch_bounds__(BLK) void k_edge_agg(const int* __restrict__ src,
                                                  const int* __restrict__ dst,
                                                  int E, int N,
                                                  const float* __restrict__ g,
                                                  float* __restrict__ agg) {
    size_t t = (size_t)blockIdx.x * BLK + threadIdx.x;
    int e = (int)(t / F);
    int f = (int)(t & (F - 1));
    if (e >= E) return;
    int s = src[e], d = dst[e];
    if ((unsigned)s >= (unsigned)N || (unsigned)d >= (unsigned)N) return;
    atomicAdd(&agg[(size_t)d * F + f], g[(size_t)s * F + f]);
}
__global__ __launch_bounds__(BLK) void k_node1(const float* __restrict__ g1,
                                               const float* __restrict__ agg1,
                                               const float* __restrict__ dinv,
                                               const float* __restrict__ b1,
                                               const float* __restrict__ W2,
                                               float* __restrict__ g2, int N) {
    __shared__ float sW[16 * 8];
    __shared__ float sb[16];
    for (int t = threadIdx.x; t < 128; t += BLK) sW[t] = W2[t];
    if (threadIdx.x < 16) sb[threadIdx.x] = b1[threadIdx.x];
    __syncthreads();
    int i = blockIdx.x * BLK + threadIdx.x;
    if (i >= N) return;
    float di = dinv[i];
    const float4* gp = (const float4*)(g1 + (size_t)i * 16);
    const float4* ap = (const float4*)(agg1 + (size_t)i * 16);
    float h[16];
#pragma unroll
    for (int q = 0; q < 4; ++q) {
        float4 gv = gp[q], av = ap[q];
        h[4*q+0] = fmaxf((av.x + gv.x) * di + sb[4*q+0], 0.f);
        h[4*q+1] = fmaxf((av.y + gv.y) * di + sb[4*q+1], 0.f);
        h[4*q+2] = fmaxf((av.z + gv.z) * di + sb[4*q+2], 0.f);
        h[4*q+3] = fmaxf((av.w + gv.w) * di + sb[4*q+3], 0.f);
    }
    float o[8];
#pragma unroll
    for (int j = 0; j < 8; ++j) {
        float a = 0.f;
#pragma unroll
        for (int k = 0; k < 16; ++k) a += h[k] * sW[k * 8 + j];
        o[j] = a * di;
    }
    float4* op = (float4*)(g2 + (size_t)i * 8);
    op[0] = make_float4(o[0], o[1], o[2], o[3]);
    op[1] = make_float4(o[4], o[5], o[6], o[7]);
}
__global__ __launch_bounds__(BLK) void k_node2(const float* __restrict__ g2,
                                               const float* __restrict__ agg2,
                                               const float* __restrict__ dinv,
                                               const float* __restrict__ b2,
                                               const float* __restrict__ Wfc,
                                               const float* __restrict__ bfc,
                                               float* __restrict__ out, int N) {
    __shared__ float sW[8 * 4];
    __shared__ float sb2[8];
    __shared__ float sbf[4];
    if (threadIdx.x < 32) sW[threadIdx.x] = Wfc[threadIdx.x];
    if (threadIdx.x < 8) sb2[threadIdx.x] = b2[threadIdx.x];
    if (threadIdx.x < 4) sbf[threadIdx.x] = bfc[threadIdx.x];
    __syncthreads();
    int i = blockIdx.x * BLK + threadIdx.x;
    if (i >= N) return;
    float di = dinv[i];
    const float4* gp = (const float4*)(g2 + (size_t)i * 8);
    const float4* ap = (const float4*)(agg2 + (size_t)i * 8);
    float h[8];
#pragma unroll
    for (int q = 0; q < 2; ++q) {
        float4 gv = gp[q], av = ap[q];
        h[4*q+0] = fmaxf((av.x + gv.x) * di + sb2[4*q+0], 0.f);
        h[4*q+1] = fmaxf((av.y + gv.y) * di + sb2[4*q+1], 0.f);
        h[4*q+2] = fmaxf((av.z + gv.z) * di + sb2[4*q+2], 0.f);
        h[4*q+3] = fmaxf((av.w + gv.w) * di + sb2[4*q+3], 0.f);
    }
    float o[4];
#pragma unroll
    for (int k = 0; k < 4; ++k) {
        float a = sbf[k];
#pragma unroll
        for (int j = 0; j < 8; ++j) a += h[j] * sW[j * 4 + k];
        o[k] = a;
    }
    ((float4*)(out + (size_t)i * 4))[0] = make_float4(o[0], o[1], o[2], o[3]);
}

// ===================== launch =====================

extern "C" void kernel_launch(void* const* d_in, const int* in_sizes, int n_in,
                              void* d_out, int out_size, void* d_ws, size_t ws_size,
                              hipStream_t stream) {
    const float* x   = (const float*)d_in[0];
    const int*   ei  = (const int*)d_in[1];
    const float* W1  = (const float*)d_in[2];
    const float* b1  = (const float*)d_in[3];
    const float* W2  = (const float*)d_in[4];
    const float* b2  = (const float*)d_in[5];
    const float* Wfc = (const float*)d_in[6];
    const float* bfc = (const float*)d_in[7];

    int N = in_sizes[0] / 32;
    int E = in_sizes[1] / 2;
    const int* src = ei;
    const int* dst = ei + (size_t)E;

    // fast-path workspace (words of 4B)
    size_t w_g1h = 0;                                 // 8N  (16 halves/node)
    size_t w_g2  = w_g1h + (size_t)8 * N;             // 8N  f32
    size_t w_dinv= w_g2 + (size_t)8 * N;              // N
    size_t w_rp  = w_dinv + (size_t)N;                // N+1
    size_t w_cur = w_rp + (size_t)N + 1;              // N
    size_t w_bc  = w_cur + (size_t)N;                 // 256
    size_t w_bs  = w_bc + MAXB;                       // 257
    size_t w_cb  = w_bs + MAXB + 1;                   // 256
    size_t w_bin = (w_cb + MAXB + 3) & ~(size_t)3;    // E
    size_t w_csr = w_bin + (size_t)E;                 // E
    size_t need  = (w_csr + (size_t)E) * 4;

    bool fast = (ws_size >= need) && (N <= (1 << SRCBITS));

    if (fast) {
        float*    ws     = (float*)d_ws;
        __half*   g1h    = (__half*)(ws + w_g1h);
        float*    g2     = ws + w_g2;
        float*    dinv   = ws + w_dinv;
        int*      rp     = (int*)(ws + w_rp);
        int*      curN   = (int*)(ws + w_cur);
        int*      bcnt   = (int*)(ws + w_bc);
        int*      baseB  = (int*)(ws + w_bs);
        int*      curB   = (int*)(ws + w_cb);
        unsigned* binned = (unsigned*)(ws + w_bin);
        unsigned* csr    = (unsigned*)(ws + w_csr);

        int nbuk = (N + BSZ - 1) >> SHIFT;
        int nbin = (E + TILE - 1) / TILE;
        int nnode = (N + BLK - 1) / BLK;
        int nagg = (N + (BLK / 64) - 1) / (BLK / 64);

        hipMemsetAsync(bcnt, 0, MAXB * 4, stream);

        k_bcount<<<nbin, BLK, 0, stream>>>(dst, E, N, bcnt);
        k_bscan<<<1, MAXB, 0, stream>>>(bcnt, baseB, curB);
        k_binA<<<nbin, BLK, 0, stream>>>(src, dst, E, N, curB, binned);
        k_dinvB2<<<nbuk, BSZ, 0, stream>>>(binned, baseB, N, dinv, rp, curN);
        k_csr<<<dim3(nbuk, NCC), 1024, 0, stream>>>(binned, baseB, curN, csr);
        k_transform1h<<<nnode, BLK, 0, stream>>>(x, W1, dinv, g1h, N);
        k_agg1<<<nagg, BLK, 0, stream>>>(rp, csr, g1h, dinv, b1, W2, g2, N);
        k_agg2<<<nagg, BLK, 0, stream>>>(rp, csr, g2, dinv, b2, Wfc, bfc,
                                         (float*)d_out, N);
    } else {
        // round-1 atomic fallback
        float* ws   = (float*)d_ws;
        float* dinv = ws;                       // N
        float* g1   = dinv + (size_t)N;         // 16N
        float* agg1 = g1 + (size_t)16 * N;      // 16N
        float* g2   = agg1 + (size_t)16 * N;    // 8N
        float* agg2 = g2 + (size_t)8 * N;       // 8N

        hipMemsetAsync(dinv, 0, (size_t)N * 4, stream);
        hipMemsetAsync(agg1, 0, (size_t)16 * N * 4, stream);
        hipMemsetAsync(agg2, 0, (size_t)8 * N * 4, stream);

        k_count<<<(E + BLK - 1) / BLK, BLK, 0, stream>>>(dst, E, N, dinv);
        k_dinv_f<<<(N + BLK - 1) / BLK, BLK, 0, stream>>>(dinv, N);
        k_transform1<<<(N + BLK - 1) / BLK, BLK, 0, stream>>>(x, W1, dinv, g1, N);
        {
            size_t tot = (size_t)E * 16;
            k_edge_agg<16><<<(unsigned)((tot + BLK - 1) / BLK), BLK, 0, stream>>>(src, dst, E, N, g1, agg1);
        }
        k_node1<<<(N + BLK - 1) / BLK, BLK, 0, stream>>>(g1, agg1, dinv, b1, W2, g2, N);
        {
            size_t tot = (size_t)E * 8;
            k_edge_agg<8><<<(unsigned)((tot + BLK - 1) / BLK), BLK, 0, stream>>>(src, dst, E, N, g2, agg2);
        }
        k_node2<<<(N + BLK - 1) / BLK, BLK, 0, stream>>>(g2, agg2, dinv, b2, Wfc, bfc, (float*)d_out, N);
    }
}

// Round 6
// 288.868 us; speedup vs baseline: 4.0680x; 1.2360x over previous
//
#include <hip/hip_runtime.h>
#include <hip/hip_fp16.h>

#define BLK 256
#define SHIFT 9
#define BSZ 512              // node-ids per bucket
#define MAXB 256             // max buckets; requires N <= 131072
#define SRCBITS 17
#define SRCMASK ((1u << SRCBITS) - 1u)
#define TILE 4096            // edges per binning block

// ===================== binning (proven r4/r5) =====================

__global__ __launch_bounds__(BLK) void k_bcount(const int* __restrict__ dst, int E, int N,
                                                int* __restrict__ bucketcnt) {
    __shared__ int c[MAXB];
    for (int i = threadIdx.x; i < MAXB; i += BLK) c[i] = 0;
    __syncthreads();
    size_t ebase = (size_t)blockIdx.x * TILE;
#pragma unroll
    for (int q = 0; q < TILE / BLK; ++q) {
        size_t e = ebase + (size_t)q * BLK + threadIdx.x;
        if (e < (size_t)E) {
            int d = dst[e];
            if ((unsigned)d < (unsigned)N) atomicAdd(&c[d >> SHIFT], 1);
        }
    }
    __syncthreads();
    for (int i = threadIdx.x; i < MAXB; i += BLK) {
        int v = c[i];
        if (v) atomicAdd(&bucketcnt[i], v);
    }
}

__global__ __launch_bounds__(MAXB) void k_bscan(const int* __restrict__ bucketcnt,
                                                int* __restrict__ base,
                                                int* __restrict__ cursor) {
    __shared__ int s[MAXB];
    int t = threadIdx.x;
    int v = bucketcnt[t];
    s[t] = v;
    __syncthreads();
    for (int off = 1; off < MAXB; off <<= 1) {
        int u = (t >= off) ? s[t - off] : 0;
        __syncthreads();
        s[t] += u;
        __syncthreads();
    }
    int excl = s[t] - v;
    base[t] = excl;
    cursor[t] = excl;
    if (t == MAXB - 1) base[MAXB] = s[t];
}

__global__ __launch_bounds__(BLK) void k_binA(const int* __restrict__ src,
                                              const int* __restrict__ dst, int E, int N,
                                              int* __restrict__ cursor,
                                              unsigned* __restrict__ binned) {
    __shared__ int cnt[MAXB];
    __shared__ int excl[MAXB];
    __shared__ int gb[MAXB];
    __shared__ int sscan[MAXB];
    __shared__ unsigned sw[TILE];
    __shared__ unsigned char sbk[TILE];
    int t = threadIdx.x;
    for (int i = t; i < MAXB; i += BLK) cnt[i] = 0;
    __syncthreads();
    size_t ebase = (size_t)blockIdx.x * TILE;
    unsigned ww[TILE / BLK];
    int rr[TILE / BLK];
    int bb[TILE / BLK];
#pragma unroll
    for (int q = 0; q < TILE / BLK; ++q) {
        size_t e = ebase + (size_t)q * BLK + t;
        bb[q] = -1;
        if (e < (size_t)E) {
            int d = dst[e], s0 = src[e];
            if ((unsigned)d < (unsigned)N && (unsigned)s0 < (unsigned)N) {
                int b = d >> SHIFT;
                ww[q] = (unsigned)s0 | ((unsigned)(d & (BSZ - 1)) << SRCBITS);
                rr[q] = atomicAdd(&cnt[b], 1);
                bb[q] = b;
            }
        }
    }
    __syncthreads();
    int v = cnt[t];
    sscan[t] = v;
    __syncthreads();
    for (int off = 1; off < MAXB; off <<= 1) {
        int u = (t >= off) ? sscan[t - off] : 0;
        __syncthreads();
        sscan[t] += u;
        __syncthreads();
    }
    excl[t] = sscan[t] - v;
    if (v > 0) gb[t] = atomicAdd(&cursor[t], v);
    __syncthreads();
    int total = sscan[MAXB - 1];
#pragma unroll
    for (int q = 0; q < TILE / BLK; ++q) {
        if (bb[q] >= 0) {
            int p = excl[bb[q]] + rr[q];
            sw[p] = ww[q];
            sbk[p] = (unsigned char)bb[q];
        }
    }
    __syncthreads();
    for (int p = t; p < total; p += BLK) {
        int b = sbk[p];
        binned[(size_t)gb[b] + (p - excl[b])] = sw[p];
    }
}

// ===================== fused per-bucket build: dinv + rp + csr =====================

__global__ __launch_bounds__(1024) void k_buildB(const unsigned* __restrict__ binned,
                                                 const int* __restrict__ baseB, int N,
                                                 float* __restrict__ dinv,
                                                 int* __restrict__ rp,
                                                 unsigned* __restrict__ csr) {
    __shared__ int h[BSZ];
    __shared__ int sc[BSZ];
    __shared__ int cnt[BSZ];
    __shared__ int sbase[BSZ];
    int b = blockIdx.x;
    int t = threadIdx.x;
    if (t < BSZ) h[t] = 0;
    __syncthreads();
    int bb = baseB[b], be = baseB[b + 1];
    for (int k = bb + t; k < be; k += 1024) atomicAdd(&h[binned[k] >> SRCBITS], 1);
    __syncthreads();
    if (t < BSZ) sc[t] = h[t];
    __syncthreads();
    for (int off = 1; off < BSZ; off <<= 1) {
        int u = 0;
        if (t < BSZ && t >= off) u = sc[t - off];
        __syncthreads();
        if (t < BSZ) sc[t] += u;
        __syncthreads();
    }
    if (t < BSZ) {
        int v = h[t];
        int excl = sc[t] - v;
        int gnode = (b << SHIFT) + t;
        if (gnode < N) {
            rp[gnode] = bb + excl;
            dinv[gnode] = rsqrtf((float)v + 1.0f);
        }
        if (t == BSZ - 1) {
            int endn = (b << SHIFT) + BSZ;
            if (endn > N) endn = N;
            rp[endn] = bb + sc[t];
        }
        sbase[t] = bb + excl;
        cnt[t] = 0;
    }
    __syncthreads();
    for (int k = bb + t; k < be; k += 1024) {
        unsigned v = binned[k];
        int node = v >> SRCBITS;
        int r = atomicAdd(&cnt[node], 1);
        csr[sbase[node] + r] = v & SRCMASK;
    }
}

// ===================== transform =====================

union Pk8 { __half h[8]; uint4 u; };
union H2U { unsigned u; __half2 h; };

// g1h[i][0..16) = half((x[i] @ W1) * dinv[i])   (32 -> 16)
__global__ __launch_bounds__(BLK) void k_transform1h(const float* __restrict__ x,
                                                     const float* __restrict__ W1,
                                                     const float* __restrict__ dinv,
                                                     __half* __restrict__ g1h, int N) {
    __shared__ float sW[32 * 16];
    for (int t = threadIdx.x; t < 512; t += BLK) sW[t] = W1[t];
    __syncthreads();
    int i = blockIdx.x * BLK + threadIdx.x;
    if (i >= N) return;
    float xr[32];
    const float4* xp = (const float4*)(x + (size_t)i * 32);
#pragma unroll
    for (int q = 0; q < 8; ++q) {
        float4 v = xp[q];
        xr[4*q] = v.x; xr[4*q+1] = v.y; xr[4*q+2] = v.z; xr[4*q+3] = v.w;
    }
    float di = dinv[i];
    Pk8 p0, p1;
#pragma unroll
    for (int j = 0; j < 16; ++j) {
        float a = 0.f;
#pragma unroll
        for (int k = 0; k < 32; ++k) a += xr[k] * sW[k * 16 + j];
        if (j < 8) p0.h[j] = __float2half_rn(a * di);
        else       p1.h[j - 8] = __float2half_rn(a * di);
    }
    uint4* gp = (uint4*)(g1h + (size_t)i * 16);
    gp[0] = p0.u;
    gp[1] = p1.u;
}

// ===================== vectorized register-acc aggregation =====================

// wave per node; 16 edge-slots x (4 lanes x 4 features via uint2=4 halves).
// butterfly reduce; fused epilogue + 16->8 transform + prescale -> g2 (f32)
__global__ __launch_bounds__(BLK) void k_agg1(const int* __restrict__ rp,
                                              const unsigned* __restrict__ csr,
                                              const __half* __restrict__ g1h,
                                              const float* __restrict__ dinv,
                                              const float* __restrict__ b1,
                                              const float* __restrict__ W2,
                                              float* __restrict__ g2, int N) {
    __shared__ float sW[16 * 8];
    __shared__ float sb[16];
    if (threadIdx.x < 128) sW[threadIdx.x] = W2[threadIdx.x];
    if (threadIdx.x < 16) sb[threadIdx.x] = b1[threadIdx.x];
    __syncthreads();
    int wid = blockIdx.x * (BLK / 64) + (threadIdx.x >> 6);
    if (wid >= N) return;  // wave-uniform
    int lane = threadIdx.x & 63;
    int c4 = lane & 3;        // feature chunk: 4*c4 .. 4*c4+3
    int slot = lane >> 2;     // 0..15
    int base_ = rp[wid], end = rp[wid + 1];
    float a0 = 0.f, a1 = 0.f, a2 = 0.f, a3 = 0.f;
    int k = base_ + slot;
    for (; k + 16 < end; k += 32) {
        unsigned s0 = csr[k], s1 = csr[k + 16];
        uint2 u0 = *(const uint2*)(g1h + (size_t)s0 * 16 + (c4 << 2));
        uint2 u1 = *(const uint2*)(g1h + (size_t)s1 * 16 + (c4 << 2));
        H2U x0, x1, y0, y1;
        x0.u = u0.x; y0.u = u0.y; x1.u = u1.x; y1.u = u1.y;
        float2 f0 = __half22float2(x0.h), f1 = __half22float2(y0.h);
        float2 f2 = __half22float2(x1.h), f3 = __half22float2(y1.h);
        a0 += f0.x + f2.x; a1 += f0.y + f2.y;
        a2 += f1.x + f3.x; a3 += f1.y + f3.y;
    }
    if (k < end) {
        unsigned s0 = csr[k];
        uint2 u0 = *(const uint2*)(g1h + (size_t)s0 * 16 + (c4 << 2));
        H2U x0, y0;
        x0.u = u0.x; y0.u = u0.y;
        float2 f0 = __half22float2(x0.h), f1 = __half22float2(y0.h);
        a0 += f0.x; a1 += f0.y; a2 += f1.x; a3 += f1.y;
    }
#pragma unroll
    for (int m = 4; m <= 32; m <<= 1) {
        a0 += __shfl_xor(a0, m);
        a1 += __shfl_xor(a1, m);
        a2 += __shfl_xor(a2, m);
        a3 += __shfl_xor(a3, m);
    }
    float di = dinv[wid];
    uint2 su = *(const uint2*)(g1h + (size_t)wid * 16 + (c4 << 2));
    H2U sx, sy;
    sx.u = su.x; sy.u = su.y;
    float2 sf0 = __half22float2(sx.h), sf1 = __half22float2(sy.h);
    float hh[4];
    hh[0] = fmaxf((a0 + sf0.x) * di + sb[4*c4+0], 0.f);
    hh[1] = fmaxf((a1 + sf0.y) * di + sb[4*c4+1], 0.f);
    hh[2] = fmaxf((a2 + sf1.x) * di + sb[4*c4+2], 0.f);
    hh[3] = fmaxf((a3 + sf1.y) * di + sb[4*c4+3], 0.f);
    // 16 -> 8: o = lane&7 (dup x8); H[kk] lives on lane g4+(kk>>2), reg kk&3
    int g4 = lane & ~3;
    int o = lane & 7;
    float a = 0.f;
#pragma unroll
    for (int kk = 0; kk < 16; ++kk) {
        float hv = __shfl(hh[kk & 3], g4 + (kk >> 2));
        a += hv * sW[kk * 8 + o];
    }
    if (lane < 8) g2[(size_t)wid * 8 + lane] = a * di;
}

// wave per node; 16 edge-slots x (4 lanes x 2 features via float2).
// fused epilogue + final fc (8->4)+bias -> out
__global__ __launch_bounds__(BLK) void k_agg2(const int* __restrict__ rp,
                                              const unsigned* __restrict__ csr,
                                              const float* __restrict__ g2,
                                              const float* __restrict__ dinv,
                                              const float* __restrict__ b2,
                                              const float* __restrict__ Wfc,
                                              const float* __restrict__ bfc,
                                              float* __restrict__ out, int N) {
    __shared__ float sW[8 * 4];
    __shared__ float sb2[8];
    __shared__ float sbf[4];
    if (threadIdx.x < 32) sW[threadIdx.x] = Wfc[threadIdx.x];
    if (threadIdx.x < 8) sb2[threadIdx.x] = b2[threadIdx.x];
    if (threadIdx.x < 4) sbf[threadIdx.x] = bfc[threadIdx.x];
    __syncthreads();
    int wid = blockIdx.x * (BLK / 64) + (threadIdx.x >> 6);
    if (wid >= N) return;
    int lane = threadIdx.x & 63;
    int c4 = lane & 3;        // feature pair: 2*c4, 2*c4+1
    int slot = lane >> 2;     // 0..15
    int base_ = rp[wid], end = rp[wid + 1];
    float a0 = 0.f, a1 = 0.f;
    int k = base_ + slot;
    for (; k + 16 < end; k += 32) {
        unsigned s0 = csr[k], s1 = csr[k + 16];
        float2 f0 = *(const float2*)(g2 + (size_t)s0 * 8 + (c4 << 1));
        float2 f1 = *(const float2*)(g2 + (size_t)s1 * 8 + (c4 << 1));
        a0 += f0.x + f1.x;
        a1 += f0.y + f1.y;
    }
    if (k < end) {
        unsigned s0 = csr[k];
        float2 f0 = *(const float2*)(g2 + (size_t)s0 * 8 + (c4 << 1));
        a0 += f0.x; a1 += f0.y;
    }
#pragma unroll
    for (int m = 4; m <= 32; m <<= 1) {
        a0 += __shfl_xor(a0, m);
        a1 += __shfl_xor(a1, m);
    }
    float di = dinv[wid];
    float2 sf = *(const float2*)(g2 + (size_t)wid * 8 + (c4 << 1));
    float hh[2];
    hh[0] = fmaxf((a0 + sf.x) * di + sb2[2*c4+0], 0.f);
    hh[1] = fmaxf((a1 + sf.y) * di + sb2[2*c4+1], 0.f);
    // 8 -> 4: o = lane&3 (dup x16); H[j] on lane g4+(j>>1), reg j&1
    int g4 = lane & ~3;
    int o = lane & 3;
    float a = 0.f;
#pragma unroll
    for (int j = 0; j < 8; ++j) {
        float hv = __shfl(hh[j & 1], g4 + (j >> 1));
        a += hv * sW[j * 4 + o];
    }
    if (lane < 4) out[(size_t)wid * 4 + lane] = a + sbf[lane];
}

// ===================== fallback (round-1 atomic path) =====================

__global__ __launch_bounds__(BLK) void k_count(const int* __restrict__ dst, int E, int N,
                                               float* __restrict__ cnt) {
    int i = blockIdx.x * BLK + threadIdx.x;
    if (i < E) {
        int d = dst[i];
        if ((unsigned)d < (unsigned)N) atomicAdd(&cnt[d], 1.0f);
    }
}
__global__ __launch_bounds__(BLK) void k_dinv_f(float* __restrict__ cnt, int N) {
    int i = blockIdx.x * BLK + threadIdx.x;
    if (i < N) cnt[i] = rsqrtf(cnt[i] + 1.0f);
}
__global__ __launch_bounds__(BLK) void k_transform1(const float* __restrict__ x,
                                                    const float* __restrict__ W1,
                                                    const float* __restrict__ dinv,
                                                    float* __restrict__ g1, int N) {
    __shared__ float sW[32 * 16];
    for (int t = threadIdx.x; t < 512; t += BLK) sW[t] = W1[t];
    __syncthreads();
    int i = blockIdx.x * BLK + threadIdx.x;
    if (i >= N) return;
    float xr[32];
    const float4* xp = (const float4*)(x + (size_t)i * 32);
#pragma unroll
    for (int q = 0; q < 8; ++q) {
        float4 v = xp[q];
        xr[4*q] = v.x; xr[4*q+1] = v.y; xr[4*q+2] = v.z; xr[4*q+3] = v.w;
    }
    float di = dinv[i];
    float o[16];
#pragma unroll
    for (int j = 0; j < 16; ++j) {
        float a = 0.f;
#pragma unroll
        for (int k = 0; k < 32; ++k) a += xr[k] * sW[k * 16 + j];
        o[j] = a * di;
    }
    float4* gp = (float4*)(g1 + (size_t)i * 16);
#pragma unroll
    for (int q = 0; q < 4; ++q)
        gp[q] = make_float4(o[4*q], o[4*q+1], o[4*q+2], o[4*q+3]);
}
template <int F>
__global__ __launch_bounds__(BLK) void k_edge_agg(const int* __restrict__ src,
                                                  const int* __restrict__ dst,
                                                  int E, int N,
                                                  const float* __restrict__ g,
                                                  float* __restrict__ agg) {
    size_t t = (size_t)blockIdx.x * BLK + threadIdx.x;
    int e = (int)(t / F);
    int f = (int)(t & (F - 1));
    if (e >= E) return;
    int s = src[e], d = dst[e];
    if ((unsigned)s >= (unsigned)N || (unsigned)d >= (unsigned)N) return;
    atomicAdd(&agg[(size_t)d * F + f], g[(size_t)s * F + f]);
}
__global__ __launch_bounds__(BLK) void k_node1(const float* __restrict__ g1,
                                               const float* __restrict__ agg1,
                                               const float* __restrict__ dinv,
                                               const float* __restrict__ b1,
                                               const float* __restrict__ W2,
                                               float* __restrict__ g2, int N) {
    __shared__ float sW[16 * 8];
    __shared__ float sb[16];
    for (int t = threadIdx.x; t < 128; t += BLK) sW[t] = W2[t];
    if (threadIdx.x < 16) sb[threadIdx.x] = b1[threadIdx.x];
    __syncthreads();
    int i = blockIdx.x * BLK + threadIdx.x;
    if (i >= N) return;
    float di = dinv[i];
    const float4* gp = (const float4*)(g1 + (size_t)i * 16);
    const float4* ap = (const float4*)(agg1 + (size_t)i * 16);
    float h[16];
#pragma unroll
    for (int q = 0; q < 4; ++q) {
        float4 gv = gp[q], av = ap[q];
        h[4*q+0] = fmaxf((av.x + gv.x) * di + sb[4*q+0], 0.f);
        h[4*q+1] = fmaxf((av.y + gv.y) * di + sb[4*q+1], 0.f);
        h[4*q+2] = fmaxf((av.z + gv.z) * di + sb[4*q+2], 0.f);
        h[4*q+3] = fmaxf((av.w + gv.w) * di + sb[4*q+3], 0.f);
    }
    float o[8];
#pragma unroll
    for (int j = 0; j < 8; ++j) {
        float a = 0.f;
#pragma unroll
        for (int k = 0; k < 16; ++k) a += h[k] * sW[k * 8 + j];
        o[j] = a * di;
    }
    float4* op = (float4*)(g2 + (size_t)i * 8);
    op[0] = make_float4(o[0], o[1], o[2], o[3]);
    op[1] = make_float4(o[4], o[5], o[6], o[7]);
}
__global__ __launch_bounds__(BLK) void k_node2(const float* __restrict__ g2,
                                               const float* __restrict__ agg2,
                                               const float* __restrict__ dinv,
                                               const float* __restrict__ b2,
                                               const float* __restrict__ Wfc,
                                               const float* __restrict__ bfc,
                                               float* __restrict__ out, int N) {
    __shared__ float sW[8 * 4];
    __shared__ float sb2[8];
    __shared__ float sbf[4];
    if (threadIdx.x < 32) sW[threadIdx.x] = Wfc[threadIdx.x];
    if (threadIdx.x < 8) sb2[threadIdx.x] = b2[threadIdx.x];
    if (threadIdx.x < 4) sbf[threadIdx.x] = bfc[threadIdx.x];
    __syncthreads();
    int i = blockIdx.x * BLK + threadIdx.x;
    if (i >= N) return;
    float di = dinv[i];
    const float4* gp = (const float4*)(g2 + (size_t)i * 8);
    const float4* ap = (const float4*)(agg2 + (size_t)i * 8);
    float h[8];
#pragma unroll
    for (int q = 0; q < 2; ++q) {
        float4 gv = gp[q], av = ap[q];
        h[4*q+0] = fmaxf((av.x + gv.x) * di + sb2[4*q+0], 0.f);
        h[4*q+1] = fmaxf((av.y + gv.y) * di + sb2[4*q+1], 0.f);
        h[4*q+2] = fmaxf((av.z + gv.z) * di + sb2[4*q+2], 0.f);
        h[4*q+3] = fmaxf((av.w + gv.w) * di + sb2[4*q+3], 0.f);
    }
    float o[4];
#pragma unroll
    for (int k = 0; k < 4; ++k) {
        float a = sbf[k];
#pragma unroll
        for (int j = 0; j < 8; ++j) a += h[j] * sW[j * 4 + k];
        o[k] = a;
    }
    ((float4*)(out + (size_t)i * 4))[0] = make_float4(o[0], o[1], o[2], o[3]);
}

// ===================== launch =====================

extern "C" void kernel_launch(void* const* d_in, const int* in_sizes, int n_in,
                              void* d_out, int out_size, void* d_ws, size_t ws_size,
                              hipStream_t stream) {
    const float* x   = (const float*)d_in[0];
    const int*   ei  = (const int*)d_in[1];
    const float* W1  = (const float*)d_in[2];
    const float* b1  = (const float*)d_in[3];
    const float* W2  = (const float*)d_in[4];
    const float* b2  = (const float*)d_in[5];
    const float* Wfc = (const float*)d_in[6];
    const float* bfc = (const float*)d_in[7];

    int N = in_sizes[0] / 32;
    int E = in_sizes[1] / 2;
    const int* src = ei;
    const int* dst = ei + (size_t)E;

    // fast-path workspace (words of 4B)
    size_t w_g1h = 0;                                 // 8N  (16 halves/node)
    size_t w_g2  = w_g1h + (size_t)8 * N;             // 8N  f32
    size_t w_dinv= w_g2 + (size_t)8 * N;              // N
    size_t w_rp  = w_dinv + (size_t)N;                // N+1
    size_t w_bc  = w_rp + (size_t)N + 1;              // 256
    size_t w_bs  = w_bc + MAXB;                       // 257
    size_t w_cb  = w_bs + MAXB + 1;                   // 256
    size_t w_bin = (w_cb + MAXB + 3) & ~(size_t)3;    // E
    size_t w_csr = w_bin + (size_t)E;                 // E
    size_t need  = (w_csr + (size_t)E) * 4;

    bool fast = (ws_size >= need) && (N <= (1 << SRCBITS));

    if (fast) {
        float*    ws     = (float*)d_ws;
        __half*   g1h    = (__half*)(ws + w_g1h);
        float*    g2     = ws + w_g2;
        float*    dinv   = ws + w_dinv;
        int*      rp     = (int*)(ws + w_rp);
        int*      bcnt   = (int*)(ws + w_bc);
        int*      baseB  = (int*)(ws + w_bs);
        int*      curB   = (int*)(ws + w_cb);
        unsigned* binned = (unsigned*)(ws + w_bin);
        unsigned* csr    = (unsigned*)(ws + w_csr);

        int nbuk = (N + BSZ - 1) >> SHIFT;
        int nbin = (E + TILE - 1) / TILE;
        int nnode = (N + BLK - 1) / BLK;
        int nagg = (N + (BLK / 64) - 1) / (BLK / 64);

        hipMemsetAsync(bcnt, 0, MAXB * 4, stream);

        k_bcount<<<nbin, BLK, 0, stream>>>(dst, E, N, bcnt);
        k_bscan<<<1, MAXB, 0, stream>>>(bcnt, baseB, curB);
        k_binA<<<nbin, BLK, 0, stream>>>(src, dst, E, N, curB, binned);
        k_buildB<<<nbuk, 1024, 0, stream>>>(binned, baseB, N, dinv, rp, csr);
        k_transform1h<<<nnode, BLK, 0, stream>>>(x, W1, dinv, g1h, N);
        k_agg1<<<nagg, BLK, 0, stream>>>(rp, csr, g1h, dinv, b1, W2, g2, N);
        k_agg2<<<nagg, BLK, 0, stream>>>(rp, csr, g2, dinv, b2, Wfc, bfc,
                                         (float*)d_out, N);
    } else {
        // round-1 atomic fallback
        float* ws   = (float*)d_ws;
        float* dinv = ws;                       // N
        float* g1   = dinv + (size_t)N;         // 16N
        float* agg1 = g1 + (size_t)16 * N;      // 16N
        float* g2   = agg1 + (size_t)16 * N;    // 8N
        float* agg2 = g2 + (size_t)8 * N;       // 8N

        hipMemsetAsync(dinv, 0, (size_t)N * 4, stream);
        hipMemsetAsync(agg1, 0, (size_t)16 * N * 4, stream);
        hipMemsetAsync(agg2, 0, (size_t)8 * N * 4, stream);

        k_count<<<(E + BLK - 1) / BLK, BLK, 0, stream>>>(dst, E, N, dinv);
        k_dinv_f<<<(N + BLK - 1) / BLK, BLK, 0, stream>>>(dinv, N);
        k_transform1<<<(N + BLK - 1) / BLK, BLK, 0, stream>>>(x, W1, dinv, g1, N);
        {
            size_t tot = (size_t)E * 16;
            k_edge_agg<16><<<(unsigned)((tot + BLK - 1) / BLK), BLK, 0, stream>>>(src, dst, E, N, g1, agg1);
        }
        k_node1<<<(N + BLK - 1) / BLK, BLK, 0, stream>>>(g1, agg1, dinv, b1, W2, g2, N);
        {
            size_t tot = (size_t)E * 8;
            k_edge_agg<8><<<(unsigned)((tot + BLK - 1) / BLK), BLK, 0, stream>>>(src, dst, E, N, g2, agg2);
        }
        k_node2<<<(N + BLK - 1) / BLK, BLK, 0, stream>>>(g2, agg2, dinv, b2, Wfc, bfc, (float*)d_out, N);
    }
}

// Round 7
// 237.283 us; speedup vs baseline: 4.9524x; 1.2174x over previous
//
#include <hip/hip_runtime.h>
#include <hip/hip_fp16.h>

#define BLK 256
#define SHIFT 9
#define BSZ 512              // node-ids per bucket
#define MAXB 256             // max buckets; requires N <= 131072
#define SRCBITS 17
#define SRCMASK ((1u << SRCBITS) - 1u)
#define TILE2 8192           // edges per binning tile
#define BT 512               // binning block threads

// ===================== tile-local binning =====================

// group each tile's edges by bucket in LDS; write tile-contiguous binned +
// per-tile bucket offsets (bofs[tile*257 + b], [256]=total). No global atomics.
__global__ __launch_bounds__(BT) void k_binA2(const int* __restrict__ src,
                                              const int* __restrict__ dst, int E, int N,
                                              unsigned* __restrict__ binned,
                                              int* __restrict__ bofs) {
    __shared__ int cnt[MAXB];
    __shared__ int sscan[MAXB];
    __shared__ int excl[MAXB];
    __shared__ unsigned sw[TILE2];
    int t = threadIdx.x;
    if (t < MAXB) cnt[t] = 0;
    __syncthreads();
    size_t tb = (size_t)blockIdx.x * TILE2;
    unsigned wv[16];
    int rkbk[16];   // (rank<<8) | bucket, or -1
#pragma unroll
    for (int q = 0; q < 4; ++q) {
        int i4 = t + q * BT;
        size_t e0 = tb + (size_t)i4 * 4;
        int4 s4, d4;
        bool vec = (e0 + 4 <= (size_t)E);
        if (vec) {
            s4 = ((const int4*)src)[tb / 4 + i4];
            d4 = ((const int4*)dst)[tb / 4 + i4];
        }
#pragma unroll
        for (int j = 0; j < 4; ++j) {
            int idx = q * 4 + j;
            rkbk[idx] = -1;
            size_t e = e0 + j;
            int d = -1, s = -1;
            if (vec) {
                d = (j == 0) ? d4.x : (j == 1) ? d4.y : (j == 2) ? d4.z : d4.w;
                s = (j == 0) ? s4.x : (j == 1) ? s4.y : (j == 2) ? s4.z : s4.w;
            } else if (e < (size_t)E) {
                d = dst[e]; s = src[e];
            }
            if ((unsigned)d < (unsigned)N && (unsigned)s < (unsigned)N) {
                int b = d >> SHIFT;
                wv[idx] = (unsigned)s | ((unsigned)(d & (BSZ - 1)) << SRCBITS);
                int r = atomicAdd(&cnt[b], 1);
                rkbk[idx] = (r << 8) | b;
            }
        }
    }
    __syncthreads();
    if (t < MAXB) sscan[t] = cnt[t];
    __syncthreads();
    for (int off = 1; off < MAXB; off <<= 1) {
        int u = 0;
        if (t < MAXB && t >= off) u = sscan[t - off];
        __syncthreads();
        if (t < MAXB) sscan[t] += u;
        __syncthreads();
    }
    if (t < MAXB) excl[t] = sscan[t] - cnt[t];
    __syncthreads();
    int total = sscan[MAXB - 1];
#pragma unroll
    for (int idx = 0; idx < 16; ++idx) {
        int rb = rkbk[idx];
        if (rb >= 0) sw[excl[rb & 255] + (rb >> 8)] = wv[idx];
    }
    __syncthreads();
    for (int p = t; p < total; p += BT) binned[tb + p] = sw[p];
    size_t bo = (size_t)blockIdx.x * 257;
    if (t < MAXB) bofs[bo + t] = excl[t];
    if (t == 0) bofs[bo + MAXB] = total;
}

// bucket totals from bofs column diffs (1.6MB read instead of 25.6MB edge pass)
__global__ __launch_bounds__(MAXB) void k_bsum(const int* __restrict__ bofs, int ntiles,
                                               int* __restrict__ btot) {
    int t = threadIdx.x;
    int c = 0;
    for (int tl = blockIdx.x; tl < ntiles; tl += gridDim.x) {
        size_t bo = (size_t)tl * 257;
        c += bofs[bo + t + 1] - bofs[bo + t];
    }
    if (c) atomicAdd(&btot[t], c);
}

__global__ __launch_bounds__(MAXB) void k_bscan(const int* __restrict__ btot,
                                                int* __restrict__ base) {
    __shared__ int s[MAXB];
    int t = threadIdx.x;
    int v = btot[t];
    s[t] = v;
    __syncthreads();
    for (int off = 1; off < MAXB; off <<= 1) {
        int u = (t >= off) ? s[t - off] : 0;
        __syncthreads();
        s[t] += u;
        __syncthreads();
    }
    base[t] = s[t] - v;
    if (t == MAXB - 1) base[MAXB] = s[t];
}

// ===================== per-bucket build: dinv + rp + csr (segment gather) ==========

__global__ __launch_bounds__(1024) void k_buildB2(const unsigned* __restrict__ binned,
                                                  const int* __restrict__ bofs,
                                                  const int* __restrict__ baseB,
                                                  int ntiles, int N,
                                                  float* __restrict__ dinv,
                                                  int* __restrict__ rp,
                                                  unsigned* __restrict__ csr) {
    __shared__ int h[BSZ];
    __shared__ int sc[BSZ];
    __shared__ int cnt[BSZ];
    __shared__ int sbase[BSZ];
    int b = blockIdx.x;
    int t = threadIdx.x;
    if (t < BSZ) h[t] = 0;
    __syncthreads();
    int lane = t & 63, wid = t >> 6;      // 16 waves
    int sub = lane >> 4, sl = lane & 15;  // 4 segments per wave, 16 lanes each
    // pass 1: per-node histogram over all tile segments of this bucket
    for (int S = wid * 4 + sub; S < ntiles; S += 64) {
        size_t bo = (size_t)S * 257;
        int st = bofs[bo + b], en = bofs[bo + b + 1];
        size_t base = (size_t)S * TILE2;
        for (int k = st + sl; k < en; k += 16)
            atomicAdd(&h[binned[base + k] >> SRCBITS], 1);
    }
    __syncthreads();
    if (t < BSZ) sc[t] = h[t];
    __syncthreads();
    for (int off = 1; off < BSZ; off <<= 1) {
        int u = 0;
        if (t < BSZ && t >= off) u = sc[t - off];
        __syncthreads();
        if (t < BSZ) sc[t] += u;
        __syncthreads();
    }
    int bb = baseB[b];
    if (t < BSZ) {
        int v = h[t];
        int excl = sc[t] - v;
        int gnode = (b << SHIFT) + t;
        if (gnode < N) {
            rp[gnode] = bb + excl;
            dinv[gnode] = rsqrtf((float)v + 1.0f);
        }
        if (t == BSZ - 1) {
            int endn = (b << SHIFT) + BSZ;
            if (endn > N) endn = N;
            rp[endn] = bb + sc[t];
        }
        sbase[t] = bb + excl;
        cnt[t] = 0;
    }
    __syncthreads();
    // pass 2: place
    for (int S = wid * 4 + sub; S < ntiles; S += 64) {
        size_t bo = (size_t)S * 257;
        int st = bofs[bo + b], en = bofs[bo + b + 1];
        size_t base = (size_t)S * TILE2;
        for (int k = st + sl; k < en; k += 16) {
            unsigned v = binned[base + k];
            int node = v >> SRCBITS;
            int r = atomicAdd(&cnt[node], 1);
            csr[sbase[node] + r] = v & SRCMASK;
        }
    }
}

// ===================== transform =====================

union Pk8 { __half h[8]; uint4 u; };
union U4H { uint4 u; __half2 h[4]; };

// g1h[i][0..16) = half((x[i] @ W1) * dinv[i])   (32 -> 16)
__global__ __launch_bounds__(BLK) void k_transform1h(const float* __restrict__ x,
                                                     const float* __restrict__ W1,
                                                     const float* __restrict__ dinv,
                                                     __half* __restrict__ g1h, int N) {
    __shared__ float sW[32 * 16];
    for (int t = threadIdx.x; t < 512; t += BLK) sW[t] = W1[t];
    __syncthreads();
    int i = blockIdx.x * BLK + threadIdx.x;
    if (i >= N) return;
    float xr[32];
    const float4* xp = (const float4*)(x + (size_t)i * 32);
#pragma unroll
    for (int q = 0; q < 8; ++q) {
        float4 v = xp[q];
        xr[4*q] = v.x; xr[4*q+1] = v.y; xr[4*q+2] = v.z; xr[4*q+3] = v.w;
    }
    float di = dinv[i];
    Pk8 p0, p1;
#pragma unroll
    for (int j = 0; j < 16; ++j) {
        float a = 0.f;
#pragma unroll
        for (int k = 0; k < 32; ++k) a += xr[k] * sW[k * 16 + j];
        if (j < 8) p0.h[j] = __float2half_rn(a * di);
        else       p1.h[j - 8] = __float2half_rn(a * di);
    }
    uint4* gp = (uint4*)(g1h + (size_t)i * 16);
    gp[0] = p0.u;
    gp[1] = p1.u;
}

// ===================== register-acc aggregation (2 lanes per row) ==============

// wave per node; 32 edge-slots x (2 lanes x 8 halves via uint4).
__global__ __launch_bounds__(BLK) void k_agg1(const int* __restrict__ rp,
                                              const unsigned* __restrict__ csr,
                                              const __half* __restrict__ g1h,
                                              const float* __restrict__ dinv,
                                              const float* __restrict__ b1,
                                              const float* __restrict__ W2,
                                              float* __restrict__ g2, int N) {
    __shared__ float sW[16 * 8];
    __shared__ float sb[16];
    if (threadIdx.x < 128) sW[threadIdx.x] = W2[threadIdx.x];
    if (threadIdx.x < 16) sb[threadIdx.x] = b1[threadIdx.x];
    __syncthreads();
    int wid = blockIdx.x * (BLK / 64) + (threadIdx.x >> 6);
    if (wid >= N) return;  // wave-uniform
    int lane = threadIdx.x & 63;
    int half = lane & 1;      // features half*8 .. half*8+7
    int slot = lane >> 1;     // 0..31
    int base_ = rp[wid], end = rp[wid + 1];
    float a[8] = {0.f, 0.f, 0.f, 0.f, 0.f, 0.f, 0.f, 0.f};
    int k = base_ + slot;
    for (; k + 32 < end; k += 64) {
        unsigned s0 = csr[k], s1 = csr[k + 32];
        U4H u0, u1;
        u0.u = *(const uint4*)(g1h + (size_t)s0 * 16 + (half << 3));
        u1.u = *(const uint4*)(g1h + (size_t)s1 * 16 + (half << 3));
#pragma unroll
        for (int q = 0; q < 4; ++q) {
            float2 f0 = __half22float2(u0.h[q]);
            float2 f1 = __half22float2(u1.h[q]);
            a[2*q+0] += f0.x + f1.x;
            a[2*q+1] += f0.y + f1.y;
        }
    }
    if (k < end) {
        unsigned s0 = csr[k];
        U4H u0;
        u0.u = *(const uint4*)(g1h + (size_t)s0 * 16 + (half << 3));
#pragma unroll
        for (int q = 0; q < 4; ++q) {
            float2 f0 = __half22float2(u0.h[q]);
            a[2*q+0] += f0.x;
            a[2*q+1] += f0.y;
        }
    }
#pragma unroll
    for (int m = 2; m <= 32; m <<= 1) {
#pragma unroll
        for (int j = 0; j < 8; ++j) a[j] += __shfl_xor(a[j], m);
    }
    float di = dinv[wid];
    U4H su;
    su.u = *(const uint4*)(g1h + (size_t)wid * 16 + (half << 3));
    float hh[8];
#pragma unroll
    for (int q = 0; q < 4; ++q) {
        float2 sf = __half22float2(su.h[q]);
        hh[2*q+0] = fmaxf((a[2*q+0] + sf.x) * di + sb[half*8 + 2*q+0], 0.f);
        hh[2*q+1] = fmaxf((a[2*q+1] + sf.y) * di + sb[half*8 + 2*q+1], 0.f);
    }
    // 16 -> 8: feature kk lives on lane (lane&~1)+(kk>>3), reg kk&7
    int g2l = lane & ~1;
    int o = lane & 7;
    float acc = 0.f;
#pragma unroll
    for (int kk = 0; kk < 16; ++kk) {
        float hv = __shfl(hh[kk & 7], g2l + (kk >> 3));
        acc += hv * sW[kk * 8 + o];
    }
    if (lane < 8) g2[(size_t)wid * 8 + lane] = acc * di;
}

// wave per node; 32 edge-slots x (2 lanes x 4 floats via float4).
__global__ __launch_bounds__(BLK) void k_agg2(const int* __restrict__ rp,
                                              const unsigned* __restrict__ csr,
                                              const float* __restrict__ g2,
                                              const float* __restrict__ dinv,
                                              const float* __restrict__ b2,
                                              const float* __restrict__ Wfc,
                                              const float* __restrict__ bfc,
                                              float* __restrict__ out, int N) {
    __shared__ float sW[8 * 4];
    __shared__ float sb2[8];
    __shared__ float sbf[4];
    if (threadIdx.x < 32) sW[threadIdx.x] = Wfc[threadIdx.x];
    if (threadIdx.x < 8) sb2[threadIdx.x] = b2[threadIdx.x];
    if (threadIdx.x < 4) sbf[threadIdx.x] = bfc[threadIdx.x];
    __syncthreads();
    int wid = blockIdx.x * (BLK / 64) + (threadIdx.x >> 6);
    if (wid >= N) return;
    int lane = threadIdx.x & 63;
    int half = lane & 1;      // features half*4 .. half*4+3
    int slot = lane >> 1;     // 0..31
    int base_ = rp[wid], end = rp[wid + 1];
    float a0 = 0.f, a1 = 0.f, a2 = 0.f, a3 = 0.f;
    int k = base_ + slot;
    for (; k + 32 < end; k += 64) {
        unsigned s0 = csr[k], s1 = csr[k + 32];
        float4 f0 = *(const float4*)(g2 + (size_t)s0 * 8 + (half << 2));
        float4 f1 = *(const float4*)(g2 + (size_t)s1 * 8 + (half << 2));
        a0 += f0.x + f1.x; a1 += f0.y + f1.y;
        a2 += f0.z + f1.z; a3 += f0.w + f1.w;
    }
    if (k < end) {
        unsigned s0 = csr[k];
        float4 f0 = *(const float4*)(g2 + (size_t)s0 * 8 + (half << 2));
        a0 += f0.x; a1 += f0.y; a2 += f0.z; a3 += f0.w;
    }
#pragma unroll
    for (int m = 2; m <= 32; m <<= 1) {
        a0 += __shfl_xor(a0, m);
        a1 += __shfl_xor(a1, m);
        a2 += __shfl_xor(a2, m);
        a3 += __shfl_xor(a3, m);
    }
    float di = dinv[wid];
    float4 sf = *(const float4*)(g2 + (size_t)wid * 8 + (half << 2));
    float hh[4];
    hh[0] = fmaxf((a0 + sf.x) * di + sb2[half*4 + 0], 0.f);
    hh[1] = fmaxf((a1 + sf.y) * di + sb2[half*4 + 1], 0.f);
    hh[2] = fmaxf((a2 + sf.z) * di + sb2[half*4 + 2], 0.f);
    hh[3] = fmaxf((a3 + sf.w) * di + sb2[half*4 + 3], 0.f);
    // 8 -> 4: feature j on lane (lane&~1)+(j>>2), reg j&3
    int g2l = lane & ~1;
    int o = lane & 3;
    float acc = 0.f;
#pragma unroll
    for (int j = 0; j < 8; ++j) {
        float hv = __shfl(hh[j & 3], g2l + (j >> 2));
        acc += hv * sW[j * 4 + o];
    }
    if (lane < 4) out[(size_t)wid * 4 + lane] = acc + sbf[lane];
}

// ===================== fallback (round-1 atomic path) =====================

__global__ __launch_bounds__(BLK) void k_count(const int* __restrict__ dst, int E, int N,
                                               float* __restrict__ cnt) {
    int i = blockIdx.x * BLK + threadIdx.x;
    if (i < E) {
        int d = dst[i];
        if ((unsigned)d < (unsigned)N) atomicAdd(&cnt[d], 1.0f);
    }
}
__global__ __launch_bounds__(BLK) void k_dinv_f(float* __restrict__ cnt, int N) {
    int i = blockIdx.x * BLK + threadIdx.x;
    if (i < N) cnt[i] = rsqrtf(cnt[i] + 1.0f);
}
__global__ __launch_bounds__(BLK) void k_transform1(const float* __restrict__ x,
                                                    const float* __restrict__ W1,
                                                    const float* __restrict__ dinv,
                                                    float* __restrict__ g1, int N) {
    __shared__ float sW[32 * 16];
    for (int t = threadIdx.x; t < 512; t += BLK) sW[t] = W1[t];
    __syncthreads();
    int i = blockIdx.x * BLK + threadIdx.x;
    if (i >= N) return;
    float xr[32];
    const float4* xp = (const float4*)(x + (size_t)i * 32);
#pragma unroll
    for (int q = 0; q < 8; ++q) {
        float4 v = xp[q];
        xr[4*q] = v.x; xr[4*q+1] = v.y; xr[4*q+2] = v.z; xr[4*q+3] = v.w;
    }
    float di = dinv[i];
    float o[16];
#pragma unroll
    for (int j = 0; j < 16; ++j) {
        float a = 0.f;
#pragma unroll
        for (int k = 0; k < 32; ++k) a += xr[k] * sW[k * 16 + j];
        o[j] = a * di;
    }
    float4* gp = (float4*)(g1 + (size_t)i * 16);
#pragma unroll
    for (int q = 0; q < 4; ++q)
        gp[q] = make_float4(o[4*q], o[4*q+1], o[4*q+2], o[4*q+3]);
}
template <int F>
__global__ __launch_bounds__(BLK) void k_edge_agg(const int* __restrict__ src,
                                                  const int* __restrict__ dst,
                                                  int E, int N,
                                                  const float* __restrict__ g,
                                                  float* __restrict__ agg) {
    size_t t = (size_t)blockIdx.x * BLK + threadIdx.x;
    int e = (int)(t / F);
    int f = (int)(t & (F - 1));
    if (e >= E) return;
    int s = src[e], d = dst[e];
    if ((unsigned)s >= (unsigned)N || (unsigned)d >= (unsigned)N) return;
    atomicAdd(&agg[(size_t)d * F + f], g[(size_t)s * F + f]);
}
__global__ __launch_bounds__(BLK) void k_node1(const float* __restrict__ g1,
                                               const float* __restrict__ agg1,
                                               const float* __restrict__ dinv,
                                               const float* __restrict__ b1,
                                               const float* __restrict__ W2,
                                               float* __restrict__ g2, int N) {
    __shared__ float sW[16 * 8];
    __shared__ float sb[16];
    for (int t = threadIdx.x; t < 128; t += BLK) sW[t] = W2[t];
    if (threadIdx.x < 16) sb[threadIdx.x] = b1[threadIdx.x];
    __syncthreads();
    int i = blockIdx.x * BLK + threadIdx.x;
    if (i >= N) return;
    float di = dinv[i];
    const float4* gp = (const float4*)(g1 + (size_t)i * 16);
    const float4* ap = (const float4*)(agg1 + (size_t)i * 16);
    float h[16];
#pragma unroll
    for (int q = 0; q < 4; ++q) {
        float4 gv = gp[q], av = ap[q];
        h[4*q+0] = fmaxf((av.x + gv.x) * di + sb[4*q+0], 0.f);
        h[4*q+1] = fmaxf((av.y + gv.y) * di + sb[4*q+1], 0.f);
        h[4*q+2] = fmaxf((av.z + gv.z) * di + sb[4*q+2], 0.f);
        h[4*q+3] = fmaxf((av.w + gv.w) * di + sb[4*q+3], 0.f);
    }
    float o[8];
#pragma unroll
    for (int j = 0; j < 8; ++j) {
        float a = 0.f;
#pragma unroll
        for (int k = 0; k < 16; ++k) a += h[k] * sW[k * 8 + j];
        o[j] = a * di;
    }
    float4* op = (float4*)(g2 + (size_t)i * 8);
    op[0] = make_float4(o[0], o[1], o[2], o[3]);
    op[1] = make_float4(o[4], o[5], o[6], o[7]);
}
__global__ __launch_bounds__(BLK) void k_node2(const float* __restrict__ g2,
                                               const float* __restrict__ agg2,
                                               const float* __restrict__ dinv,
                                               const float* __restrict__ b2,
                                               const float* __restrict__ Wfc,
                                               const float* __restrict__ bfc,
                                               float* __restrict__ out, int N) {
    __shared__ float sW[8 * 4];
    __shared__ float sb2[8];
    __shared__ float sbf[4];
    if (threadIdx.x < 32) sW[threadIdx.x] = Wfc[threadIdx.x];
    if (threadIdx.x < 8) sb2[threadIdx.x] = b2[threadIdx.x];
    if (threadIdx.x < 4) sbf[threadIdx.x] = bfc[threadIdx.x];
    __syncthreads();
    int i = blockIdx.x * BLK + threadIdx.x;
    if (i >= N) return;
    float di = dinv[i];
    const float4* gp = (const float4*)(g2 + (size_t)i * 8);
    const float4* ap = (const float4*)(agg2 + (size_t)i * 8);
    float h[8];
#pragma unroll
    for (int q = 0; q < 2; ++q) {
        float4 gv = gp[q], av = ap[q];
        h[4*q+0] = fmaxf((av.x + gv.x) * di + sb2[4*q+0], 0.f);
        h[4*q+1] = fmaxf((av.y + gv.y) * di + sb2[4*q+1], 0.f);
        h[4*q+2] = fmaxf((av.z + gv.z) * di + sb2[4*q+2], 0.f);
        h[4*q+3] = fmaxf((av.w + gv.w) * di + sb2[4*q+3], 0.f);
    }
    float o[4];
#pragma unroll
    for (int k = 0; k < 4; ++k) {
        float a = sbf[k];
#pragma unroll
        for (int j = 0; j < 8; ++j) a += h[j] * sW[j * 4 + k];
        o[k] = a;
    }
    ((float4*)(out + (size_t)i * 4))[0] = make_float4(o[0], o[1], o[2], o[3]);
}

// ===================== launch =====================

extern "C" void kernel_launch(void* const* d_in, const int* in_sizes, int n_in,
                              void* d_out, int out_size, void* d_ws, size_t ws_size,
                              hipStream_t stream) {
    const float* x   = (const float*)d_in[0];
    const int*   ei  = (const int*)d_in[1];
    const float* W1  = (const float*)d_in[2];
    const float* b1  = (const float*)d_in[3];
    const float* W2  = (const float*)d_in[4];
    const float* b2  = (const float*)d_in[5];
    const float* Wfc = (const float*)d_in[6];
    const float* bfc = (const float*)d_in[7];

    int N = in_sizes[0] / 32;
    int E = in_sizes[1] / 2;
    const int* src = ei;
    const int* dst = ei + (size_t)E;

    int ntiles = (E + TILE2 - 1) / TILE2;

    // fast-path workspace (words of 4B)
    size_t w_g1h  = 0;                                 // 8N (16 halves/node)
    size_t w_g2   = w_g1h + (size_t)8 * N;             // 8N f32
    size_t w_dinv = w_g2 + (size_t)8 * N;              // N
    size_t w_rp   = w_dinv + (size_t)N;                // N+1
    size_t w_btot = w_rp + (size_t)N + 1;              // 256
    size_t w_bs   = w_btot + MAXB;                     // 257
    size_t w_bofs = w_bs + MAXB + 1;                   // ntiles*257
    size_t w_bin  = (w_bofs + (size_t)ntiles * 257 + 3) & ~(size_t)3;  // E
    size_t w_csr  = w_bin + (size_t)E;                 // E
    size_t need   = (w_csr + (size_t)E) * 4;

    bool fast = (ws_size >= need) && (N <= (1 << SRCBITS));

    if (fast) {
        float*    ws     = (float*)d_ws;
        __half*   g1h    = (__half*)(ws + w_g1h);
        float*    g2     = ws + w_g2;
        float*    dinv   = ws + w_dinv;
        int*      rp     = (int*)(ws + w_rp);
        int*      btot   = (int*)(ws + w_btot);
        int*      baseB  = (int*)(ws + w_bs);
        int*      bofs   = (int*)(ws + w_bofs);
        unsigned* binned = (unsigned*)(ws + w_bin);
        unsigned* csr    = (unsigned*)(ws + w_csr);

        int nbuk = (N + BSZ - 1) >> SHIFT;
        int nnode = (N + BLK - 1) / BLK;
        int nagg = (N + (BLK / 64) - 1) / (BLK / 64);

        hipMemsetAsync(btot, 0, MAXB * 4, stream);

        k_binA2<<<ntiles, BT, 0, stream>>>(src, dst, E, N, binned, bofs);
        k_bsum<<<128, MAXB, 0, stream>>>(bofs, ntiles, btot);
        k_bscan<<<1, MAXB, 0, stream>>>(btot, baseB);
        k_buildB2<<<nbuk, 1024, 0, stream>>>(binned, bofs, baseB, ntiles, N,
                                             dinv, rp, csr);
        k_transform1h<<<nnode, BLK, 0, stream>>>(x, W1, dinv, g1h, N);
        k_agg1<<<nagg, BLK, 0, stream>>>(rp, csr, g1h, dinv, b1, W2, g2, N);
        k_agg2<<<nagg, BLK, 0, stream>>>(rp, csr, g2, dinv, b2, Wfc, bfc,
                                         (float*)d_out, N);
    } else {
        // round-1 atomic fallback
        float* ws   = (float*)d_ws;
        float* dinv = ws;                       // N
        float* g1   = dinv + (size_t)N;         // 16N
        float* agg1 = g1 + (size_t)16 * N;      // 16N
        float* g2   = agg1 + (size_t)16 * N;    // 8N
        float* agg2 = g2 + (size_t)8 * N;       // 8N

        hipMemsetAsync(dinv, 0, (size_t)N * 4, stream);
        hipMemsetAsync(agg1, 0, (size_t)16 * N * 4, stream);
        hipMemsetAsync(agg2, 0, (size_t)8 * N * 4, stream);

        k_count<<<(E + BLK - 1) / BLK, BLK, 0, stream>>>(dst, E, N, dinv);
        k_dinv_f<<<(N + BLK - 1) / BLK, BLK, 0, stream>>>(dinv, N);
        k_transform1<<<(N + BLK - 1) / BLK, BLK, 0, stream>>>(x, W1, dinv, g1, N);
        {
            size_t tot = (size_t)E * 16;
            k_edge_agg<16><<<(unsigned)((tot + BLK - 1) / BLK), BLK, 0, stream>>>(src, dst, E, N, g1, agg1);
        }
        k_node1<<<(N + BLK - 1) / BLK, BLK, 0, stream>>>(g1, agg1, dinv, b1, W2, g2, N);
        {
            size_t tot = (size_t)E * 8;
            k_edge_agg<8><<<(unsigned)((tot + BLK - 1) / BLK), BLK, 0, stream>>>(src, dst, E, N, g2, agg2);
        }
        k_node2<<<(N + BLK - 1) / BLK, BLK, 0, stream>>>(g2, agg2, dinv, b2, Wfc, bfc, (float*)d_out, N);
    }
}

// Round 8
// 215.729 us; speedup vs baseline: 5.4472x; 1.0999x over previous
//
#include <hip/hip_runtime.h>
#include <hip/hip_fp16.h>

#define BLK 256
#define SHIFT 8
#define BSZ 256              // node-ids per bucket
#define MAXB 512             // scan width; requires ceil(N/BSZ) <= 512
#define SRCBITS 17
#define SRCMASK ((1u << SRCBITS) - 1u)
#define TILE2 8192           // edges per binning tile
#define BT 512               // binning block threads

// ===================== tile-local binning =====================

// group each tile's edges by bucket in LDS; write tile-contiguous binned +
// per-tile bucket offsets (bofs[tile*(MAXB+1) + b], [MAXB]=total). No global atomics.
__global__ __launch_bounds__(BT) void k_binA2(const int* __restrict__ src,
                                              const int* __restrict__ dst, int E, int N,
                                              unsigned* __restrict__ binned,
                                              int* __restrict__ bofs) {
    __shared__ int cnt[MAXB];
    __shared__ int sscan[MAXB];
    __shared__ int excl[MAXB];
    __shared__ unsigned sw[TILE2];
    int t = threadIdx.x;
    cnt[t] = 0;
    __syncthreads();
    size_t tb = (size_t)blockIdx.x * TILE2;
    unsigned wv[16];
    int rkbk[16];   // (rank<<9) | bucket, or -1
#pragma unroll
    for (int q = 0; q < 4; ++q) {
        int i4 = t + q * BT;
        size_t e0 = tb + (size_t)i4 * 4;
        int4 s4, d4;
        bool vec = (e0 + 4 <= (size_t)E);
        if (vec) {
            s4 = ((const int4*)src)[tb / 4 + i4];
            d4 = ((const int4*)dst)[tb / 4 + i4];
        }
#pragma unroll
        for (int j = 0; j < 4; ++j) {
            int idx = q * 4 + j;
            rkbk[idx] = -1;
            size_t e = e0 + j;
            int d = -1, s = -1;
            if (vec) {
                d = (j == 0) ? d4.x : (j == 1) ? d4.y : (j == 2) ? d4.z : d4.w;
                s = (j == 0) ? s4.x : (j == 1) ? s4.y : (j == 2) ? s4.z : s4.w;
            } else if (e < (size_t)E) {
                d = dst[e]; s = src[e];
            }
            if ((unsigned)d < (unsigned)N && (unsigned)s < (unsigned)N) {
                int b = d >> SHIFT;
                wv[idx] = (unsigned)s | ((unsigned)(d & (BSZ - 1)) << SRCBITS);
                int r = atomicAdd(&cnt[b], 1);
                rkbk[idx] = (r << 9) | b;
            }
        }
    }
    __syncthreads();
    sscan[t] = cnt[t];
    __syncthreads();
    for (int off = 1; off < MAXB; off <<= 1) {
        int u = (t >= off) ? sscan[t - off] : 0;
        __syncthreads();
        sscan[t] += u;
        __syncthreads();
    }
    excl[t] = sscan[t] - cnt[t];
    __syncthreads();
    int total = sscan[MAXB - 1];
#pragma unroll
    for (int idx = 0; idx < 16; ++idx) {
        int rb = rkbk[idx];
        if (rb >= 0) sw[excl[rb & 511] + (rb >> 9)] = wv[idx];
    }
    __syncthreads();
    for (int p = t; p < total; p += BT) binned[tb + p] = sw[p];
    size_t bo = (size_t)blockIdx.x * (MAXB + 1);
    bofs[bo + t] = excl[t];
    if (t == 0) bofs[bo + MAXB] = total;
}

// bucket totals from bofs column diffs
__global__ __launch_bounds__(MAXB) void k_bsum(const int* __restrict__ bofs, int ntiles,
                                               int* __restrict__ btot) {
    int t = threadIdx.x;
    int c = 0;
    for (int tl = blockIdx.x; tl < ntiles; tl += gridDim.x) {
        size_t bo = (size_t)tl * (MAXB + 1);
        c += bofs[bo + t + 1] - bofs[bo + t];
    }
    if (c) atomicAdd(&btot[t], c);
}

__global__ __launch_bounds__(MAXB) void k_bscan(const int* __restrict__ btot,
                                                int* __restrict__ base) {
    __shared__ int s[MAXB];
    int t = threadIdx.x;
    int v = btot[t];
    s[t] = v;
    __syncthreads();
    for (int off = 1; off < MAXB; off <<= 1) {
        int u = (t >= off) ? s[t - off] : 0;
        __syncthreads();
        s[t] += u;
        __syncthreads();
    }
    base[t] = s[t] - v;
    if (t == MAXB - 1) base[MAXB] = s[t];
}

// ===================== per-bucket build: dinv + rp + csr (segment gather) ==========

__global__ __launch_bounds__(1024) void k_buildB2(const unsigned* __restrict__ binned,
                                                  const int* __restrict__ bofs,
                                                  const int* __restrict__ baseB,
                                                  int ntiles, int N,
                                                  float* __restrict__ dinv,
                                                  int* __restrict__ rp,
                                                  unsigned* __restrict__ csr) {
    __shared__ int h[BSZ];
    __shared__ int sc[BSZ];
    __shared__ int cnt[BSZ];
    __shared__ int sbase[BSZ];
    int b = blockIdx.x;
    int t = threadIdx.x;
    if (t < BSZ) h[t] = 0;
    __syncthreads();
    int lane = t & 63, wid = t >> 6;      // 16 waves
    int sub = lane >> 4, sl = lane & 15;  // 4 segments per wave, 16 lanes each
    // pass 1: per-node histogram over all tile segments of this bucket
    for (int S = wid * 4 + sub; S < ntiles; S += 64) {
        size_t bo = (size_t)S * (MAXB + 1);
        int st = bofs[bo + b], en = bofs[bo + b + 1];
        size_t base = (size_t)S * TILE2;
        for (int k = st + sl; k < en; k += 16)
            atomicAdd(&h[binned[base + k] >> SRCBITS], 1);
    }
    __syncthreads();
    if (t < BSZ) sc[t] = h[t];
    __syncthreads();
    for (int off = 1; off < BSZ; off <<= 1) {
        int u = 0;
        if (t < BSZ && t >= off) u = sc[t - off];
        __syncthreads();
        if (t < BSZ) sc[t] += u;
        __syncthreads();
    }
    int bb = baseB[b];
    if (t < BSZ) {
        int v = h[t];
        int excl = sc[t] - v;
        int gnode = (b << SHIFT) + t;
        if (gnode < N) {
            rp[gnode] = bb + excl;
            dinv[gnode] = rsqrtf((float)v + 1.0f);
        }
        if (t == BSZ - 1) {
            int endn = (b << SHIFT) + BSZ;
            if (endn > N) endn = N;
            rp[endn] = bb + sc[t];
        }
        sbase[t] = bb + excl;
        cnt[t] = 0;
    }
    __syncthreads();
    // pass 2: place
    for (int S = wid * 4 + sub; S < ntiles; S += 64) {
        size_t bo = (size_t)S * (MAXB + 1);
        int st = bofs[bo + b], en = bofs[bo + b + 1];
        size_t base = (size_t)S * TILE2;
        for (int k = st + sl; k < en; k += 16) {
            unsigned v = binned[base + k];
            int node = v >> SRCBITS;
            int r = atomicAdd(&cnt[node], 1);
            csr[sbase[node] + r] = v & SRCMASK;
        }
    }
}

// ===================== transform =====================

union Pk8 { __half h[8]; uint4 u; };
union H2U { unsigned u; __half2 h; };

// g1h[i][0..16) = half((x[i] @ W1) * dinv[i])   (32 -> 16)
__global__ __launch_bounds__(BLK) void k_transform1h(const float* __restrict__ x,
                                                     const float* __restrict__ W1,
                                                     const float* __restrict__ dinv,
                                                     __half* __restrict__ g1h, int N) {
    __shared__ float sW[32 * 16];
    for (int t = threadIdx.x; t < 512; t += BLK) sW[t] = W1[t];
    __syncthreads();
    int i = blockIdx.x * BLK + threadIdx.x;
    if (i >= N) return;
    float xr[32];
    const float4* xp = (const float4*)(x + (size_t)i * 32);
#pragma unroll
    for (int q = 0; q < 8; ++q) {
        float4 v = xp[q];
        xr[4*q] = v.x; xr[4*q+1] = v.y; xr[4*q+2] = v.z; xr[4*q+3] = v.w;
    }
    float di = dinv[i];
    Pk8 p0, p1;
#pragma unroll
    for (int j = 0; j < 16; ++j) {
        float a = 0.f;
#pragma unroll
        for (int k = 0; k < 32; ++k) a += xr[k] * sW[k * 16 + j];
        if (j < 8) p0.h[j] = __float2half_rn(a * di);
        else       p1.h[j - 8] = __float2half_rn(a * di);
    }
    uint4* gp = (uint4*)(g1h + (size_t)i * 16);
    gp[0] = p0.u;
    gp[1] = p1.u;
}

// ===================== register-acc aggregation (r6-proven 4-lane layout) ==========

// wave per node; 16 edge-slots x (4 lanes x 4 features via uint2=4 halves).
__global__ __launch_bounds__(BLK) void k_agg1(const int* __restrict__ rp,
                                              const unsigned* __restrict__ csr,
                                              const __half* __restrict__ g1h,
                                              const float* __restrict__ dinv,
                                              const float* __restrict__ b1,
                                              const float* __restrict__ W2,
                                              float* __restrict__ g2, int N) {
    __shared__ float sW[16 * 8];
    __shared__ float sb[16];
    if (threadIdx.x < 128) sW[threadIdx.x] = W2[threadIdx.x];
    if (threadIdx.x < 16) sb[threadIdx.x] = b1[threadIdx.x];
    __syncthreads();
    int wid = blockIdx.x * (BLK / 64) + (threadIdx.x >> 6);
    if (wid >= N) return;  // wave-uniform
    int lane = threadIdx.x & 63;
    int c4 = lane & 3;        // feature chunk: 4*c4 .. 4*c4+3
    int slot = lane >> 2;     // 0..15
    int base_ = rp[wid], end = rp[wid + 1];
    float a0 = 0.f, a1 = 0.f, a2 = 0.f, a3 = 0.f;
    int k = base_ + slot;
    for (; k + 16 < end; k += 32) {
        unsigned s0 = csr[k], s1 = csr[k + 16];
        uint2 u0 = *(const uint2*)(g1h + (size_t)s0 * 16 + (c4 << 2));
        uint2 u1 = *(const uint2*)(g1h + (size_t)s1 * 16 + (c4 << 2));
        H2U x0, x1, y0, y1;
        x0.u = u0.x; y0.u = u0.y; x1.u = u1.x; y1.u = u1.y;
        float2 f0 = __half22float2(x0.h), f1 = __half22float2(y0.h);
        float2 f2 = __half22float2(x1.h), f3 = __half22float2(y1.h);
        a0 += f0.x + f2.x; a1 += f0.y + f2.y;
        a2 += f1.x + f3.x; a3 += f1.y + f3.y;
    }
    if (k < end) {
        unsigned s0 = csr[k];
        uint2 u0 = *(const uint2*)(g1h + (size_t)s0 * 16 + (c4 << 2));
        H2U x0, y0;
        x0.u = u0.x; y0.u = u0.y;
        float2 f0 = __half22float2(x0.h), f1 = __half22float2(y0.h);
        a0 += f0.x; a1 += f0.y; a2 += f1.x; a3 += f1.y;
    }
#pragma unroll
    for (int m = 4; m <= 32; m <<= 1) {
        a0 += __shfl_xor(a0, m);
        a1 += __shfl_xor(a1, m);
        a2 += __shfl_xor(a2, m);
        a3 += __shfl_xor(a3, m);
    }
    float di = dinv[wid];
    uint2 su = *(const uint2*)(g1h + (size_t)wid * 16 + (c4 << 2));
    H2U sx, sy;
    sx.u = su.x; sy.u = su.y;
    float2 sf0 = __half22float2(sx.h), sf1 = __half22float2(sy.h);
    float hh[4];
    hh[0] = fmaxf((a0 + sf0.x) * di + sb[4*c4+0], 0.f);
    hh[1] = fmaxf((a1 + sf0.y) * di + sb[4*c4+1], 0.f);
    hh[2] = fmaxf((a2 + sf1.x) * di + sb[4*c4+2], 0.f);
    hh[3] = fmaxf((a3 + sf1.y) * di + sb[4*c4+3], 0.f);
    // 16 -> 8: o = lane&7 (dup x8); H[kk] lives on lane g4+(kk>>2), reg kk&3
    int g4 = lane & ~3;
    int o = lane & 7;
    float a = 0.f;
#pragma unroll
    for (int kk = 0; kk < 16; ++kk) {
        float hv = __shfl(hh[kk & 3], g4 + (kk >> 2));
        a += hv * sW[kk * 8 + o];
    }
    if (lane < 8) g2[(size_t)wid * 8 + lane] = a * di;
}

// wave per node; 16 edge-slots x (4 lanes x 2 features via float2).
__global__ __launch_bounds__(BLK) void k_agg2(const int* __restrict__ rp,
                                              const unsigned* __restrict__ csr,
                                              const float* __restrict__ g2,
                                              const float* __restrict__ dinv,
                                              const float* __restrict__ b2,
                                              const float* __restrict__ Wfc,
                                              const float* __restrict__ bfc,
                                              float* __restrict__ out, int N) {
    __shared__ float sW[8 * 4];
    __shared__ float sb2[8];
    __shared__ float sbf[4];
    if (threadIdx.x < 32) sW[threadIdx.x] = Wfc[threadIdx.x];
    if (threadIdx.x < 8) sb2[threadIdx.x] = b2[threadIdx.x];
    if (threadIdx.x < 4) sbf[threadIdx.x] = bfc[threadIdx.x];
    __syncthreads();
    int wid = blockIdx.x * (BLK / 64) + (threadIdx.x >> 6);
    if (wid >= N) return;
    int lane = threadIdx.x & 63;
    int c4 = lane & 3;        // feature pair: 2*c4, 2*c4+1
    int slot = lane >> 2;     // 0..15
    int base_ = rp[wid], end = rp[wid + 1];
    float a0 = 0.f, a1 = 0.f;
    int k = base_ + slot;
    for (; k + 16 < end; k += 32) {
        unsigned s0 = csr[k], s1 = csr[k + 16];
        float2 f0 = *(const float2*)(g2 + (size_t)s0 * 8 + (c4 << 1));
        float2 f1 = *(const float2*)(g2 + (size_t)s1 * 8 + (c4 << 1));
        a0 += f0.x + f1.x;
        a1 += f0.y + f1.y;
    }
    if (k < end) {
        unsigned s0 = csr[k];
        float2 f0 = *(const float2*)(g2 + (size_t)s0 * 8 + (c4 << 1));
        a0 += f0.x; a1 += f0.y;
    }
#pragma unroll
    for (int m = 4; m <= 32; m <<= 1) {
        a0 += __shfl_xor(a0, m);
        a1 += __shfl_xor(a1, m);
    }
    float di = dinv[wid];
    float2 sf = *(const float2*)(g2 + (size_t)wid * 8 + (c4 << 1));
    float hh[2];
    hh[0] = fmaxf((a0 + sf.x) * di + sb2[2*c4+0], 0.f);
    hh[1] = fmaxf((a1 + sf.y) * di + sb2[2*c4+1], 0.f);
    // 8 -> 4: o = lane&3 (dup x16); H[j] on lane g4+(j>>1), reg j&1
    int g4 = lane & ~3;
    int o = lane & 3;
    float a = 0.f;
#pragma unroll
    for (int j = 0; j < 8; ++j) {
        float hv = __shfl(hh[j & 1], g4 + (j >> 1));
        a += hv * sW[j * 4 + o];
    }
    if (lane < 4) out[(size_t)wid * 4 + lane] = a + sbf[lane];
}

// ===================== fallback (round-1 atomic path) =====================

__global__ __launch_bounds__(BLK) void k_count(const int* __restrict__ dst, int E, int N,
                                               float* __restrict__ cnt) {
    int i = blockIdx.x * BLK + threadIdx.x;
    if (i < E) {
        int d = dst[i];
        if ((unsigned)d < (unsigned)N) atomicAdd(&cnt[d], 1.0f);
    }
}
__global__ __launch_bounds__(BLK) void k_dinv_f(float* __restrict__ cnt, int N) {
    int i = blockIdx.x * BLK + threadIdx.x;
    if (i < N) cnt[i] = rsqrtf(cnt[i] + 1.0f);
}
__global__ __launch_bounds__(BLK) void k_transform1(const float* __restrict__ x,
                                                    const float* __restrict__ W1,
                                                    const float* __restrict__ dinv,
                                                    float* __restrict__ g1, int N) {
    __shared__ float sW[32 * 16];
    for (int t = threadIdx.x; t < 512; t += BLK) sW[t] = W1[t];
    __syncthreads();
    int i = blockIdx.x * BLK + threadIdx.x;
    if (i >= N) return;
    float xr[32];
    const float4* xp = (const float4*)(x + (size_t)i * 32);
#pragma unroll
    for (int q = 0; q < 8; ++q) {
        float4 v = xp[q];
        xr[4*q] = v.x; xr[4*q+1] = v.y; xr[4*q+2] = v.z; xr[4*q+3] = v.w;
    }
    float di = dinv[i];
    float o[16];
#pragma unroll
    for (int j = 0; j < 16; ++j) {
        float a = 0.f;
#pragma unroll
        for (int k = 0; k < 32; ++k) a += xr[k] * sW[k * 16 + j];
        o[j] = a * di;
    }
    float4* gp = (float4*)(g1 + (size_t)i * 16);
#pragma unroll
    for (int q = 0; q < 4; ++q)
        gp[q] = make_float4(o[4*q], o[4*q+1], o[4*q+2], o[4*q+3]);
}
template <int F>
__global__ __launch_bounds__(BLK) void k_edge_agg(const int* __restrict__ src,
                                                  const int* __restrict__ dst,
                                                  int E, int N,
                                                  const float* __restrict__ g,
                                                  float* __restrict__ agg) {
    size_t t = (size_t)blockIdx.x * BLK + threadIdx.x;
    int e = (int)(t / F);
    int f = (int)(t & (F - 1));
    if (e >= E) return;
    int s = src[e], d = dst[e];
    if ((unsigned)s >= (unsigned)N || (unsigned)d >= (unsigned)N) return;
    atomicAdd(&agg[(size_t)d * F + f], g[(size_t)s * F + f]);
}
__global__ __launch_bounds__(BLK) void k_node1(const float* __restrict__ g1,
                                               const float* __restrict__ agg1,
                                               const float* __restrict__ dinv,
                                               const float* __restrict__ b1,
                                               const float* __restrict__ W2,
                                               float* __restrict__ g2, int N) {
    __shared__ float sW[16 * 8];
    __shared__ float sb[16];
    for (int t = threadIdx.x; t < 128; t += BLK) sW[t] = W2[t];
    if (threadIdx.x < 16) sb[threadIdx.x] = b1[threadIdx.x];
    __syncthreads();
    int i = blockIdx.x * BLK + threadIdx.x;
    if (i >= N) return;
    float di = dinv[i];
    const float4* gp = (const float4*)(g1 + (size_t)i * 16);
    const float4* ap = (const float4*)(agg1 + (size_t)i * 16);
    float h[16];
#pragma unroll
    for (int q = 0; q < 4; ++q) {
        float4 gv = gp[q], av = ap[q];
        h[4*q+0] = fmaxf((av.x + gv.x) * di + sb[4*q+0], 0.f);
        h[4*q+1] = fmaxf((av.y + gv.y) * di + sb[4*q+1], 0.f);
        h[4*q+2] = fmaxf((av.z + gv.z) * di + sb[4*q+2], 0.f);
        h[4*q+3] = fmaxf((av.w + gv.w) * di + sb[4*q+3], 0.f);
    }
    float o[8];
#pragma unroll
    for (int j = 0; j < 8; ++j) {
        float a = 0.f;
#pragma unroll
        for (int k = 0; k < 16; ++k) a += h[k] * sW[k * 8 + j];
        o[j] = a * di;
    }
    float4* op = (float4*)(g2 + (size_t)i * 8);
    op[0] = make_float4(o[0], o[1], o[2], o[3]);
    op[1] = make_float4(o[4], o[5], o[6], o[7]);
}
__global__ __launch_bounds__(BLK) void k_node2(const float* __restrict__ g2,
                                               const float* __restrict__ agg2,
                                               const float* __restrict__ dinv,
                                               const float* __restrict__ b2,
                                               const float* __restrict__ Wfc,
                                               const float* __restrict__ bfc,
                                               float* __restrict__ out, int N) {
    __shared__ float sW[8 * 4];
    __shared__ float sb2[8];
    __shared__ float sbf[4];
    if (threadIdx.x < 32) sW[threadIdx.x] = Wfc[threadIdx.x];
    if (threadIdx.x < 8) sb2[threadIdx.x] = b2[threadIdx.x];
    if (threadIdx.x < 4) sbf[threadIdx.x] = bfc[threadIdx.x];
    __syncthreads();
    int i = blockIdx.x * BLK + threadIdx.x;
    if (i >= N) return;
    float di = dinv[i];
    const float4* gp = (const float4*)(g2 + (size_t)i * 8);
    const float4* ap = (const float4*)(agg2 + (size_t)i * 8);
    float h[8];
#pragma unroll
    for (int q = 0; q < 2; ++q) {
        float4 gv = gp[q], av = ap[q];
        h[4*q+0] = fmaxf((av.x + gv.x) * di + sb2[4*q+0], 0.f);
        h[4*q+1] = fmaxf((av.y + gv.y) * di + sb2[4*q+1], 0.f);
        h[4*q+2] = fmaxf((av.z + gv.z) * di + sb2[4*q+2], 0.f);
        h[4*q+3] = fmaxf((av.w + gv.w) * di + sb2[4*q+3], 0.f);
    }
    float o[4];
#pragma unroll
    for (int k = 0; k < 4; ++k) {
        float a = sbf[k];
#pragma unroll
        for (int j = 0; j < 8; ++j) a += h[j] * sW[j * 4 + k];
        o[k] = a;
    }
    ((float4*)(out + (size_t)i * 4))[0] = make_float4(o[0], o[1], o[2], o[3]);
}

// ===================== launch =====================

extern "C" void kernel_launch(void* const* d_in, const int* in_sizes, int n_in,
                              void* d_out, int out_size, void* d_ws, size_t ws_size,
                              hipStream_t stream) {
    const float* x   = (const float*)d_in[0];
    const int*   ei  = (const int*)d_in[1];
    const float* W1  = (const float*)d_in[2];
    const float* b1  = (const float*)d_in[3];
    const float* W2  = (const float*)d_in[4];
    const float* b2  = (const float*)d_in[5];
    const float* Wfc = (const float*)d_in[6];
    const float* bfc = (const float*)d_in[7];

    int N = in_sizes[0] / 32;
    int E = in_sizes[1] / 2;
    const int* src = ei;
    const int* dst = ei + (size_t)E;

    int ntiles = (E + TILE2 - 1) / TILE2;
    int nbuk = (N + BSZ - 1) >> SHIFT;

    // fast-path workspace (words of 4B)
    size_t w_g1h  = 0;                                 // 8N (16 halves/node)
    size_t w_g2   = w_g1h + (size_t)8 * N;             // 8N f32
    size_t w_dinv = w_g2 + (size_t)8 * N;              // N
    size_t w_rp   = w_dinv + (size_t)N;                // N+1
    size_t w_btot = w_rp + (size_t)N + 1;              // MAXB
    size_t w_bs   = w_btot + MAXB;                     // MAXB+1
    size_t w_bofs = w_bs + MAXB + 1;                   // ntiles*(MAXB+1)
    size_t w_bin  = (w_bofs + (size_t)ntiles * (MAXB + 1) + 3) & ~(size_t)3;  // E
    size_t w_csr  = w_bin + (size_t)E;                 // E
    size_t need   = (w_csr + (size_t)E) * 4;

    bool fast = (ws_size >= need) && (N <= (1 << SRCBITS)) && (nbuk <= MAXB);

    if (fast) {
        float*    ws     = (float*)d_ws;
        __half*   g1h    = (__half*)(ws + w_g1h);
        float*    g2     = ws + w_g2;
        float*    dinv   = ws + w_dinv;
        int*      rp     = (int*)(ws + w_rp);
        int*      btot   = (int*)(ws + w_btot);
        int*      baseB  = (int*)(ws + w_bs);
        int*      bofs   = (int*)(ws + w_bofs);
        unsigned* binned = (unsigned*)(ws + w_bin);
        unsigned* csr    = (unsigned*)(ws + w_csr);

        int nnode = (N + BLK - 1) / BLK;
        int nagg = (N + (BLK / 64) - 1) / (BLK / 64);

        hipMemsetAsync(btot, 0, MAXB * 4, stream);

        k_binA2<<<ntiles, BT, 0, stream>>>(src, dst, E, N, binned, bofs);
        k_bsum<<<128, MAXB, 0, stream>>>(bofs, ntiles, btot);
        k_bscan<<<1, MAXB, 0, stream>>>(btot, baseB);
        k_buildB2<<<nbuk, 1024, 0, stream>>>(binned, bofs, baseB, ntiles, N,
                                             dinv, rp, csr);
        k_transform1h<<<nnode, BLK, 0, stream>>>(x, W1, dinv, g1h, N);
        k_agg1<<<nagg, BLK, 0, stream>>>(rp, csr, g1h, dinv, b1, W2, g2, N);
        k_agg2<<<nagg, BLK, 0, stream>>>(rp, csr, g2, dinv, b2, Wfc, bfc,
                                         (float*)d_out, N);
    } else {
        // round-1 atomic fallback
        float* ws   = (float*)d_ws;
        float* dinv = ws;                       // N
        float* g1   = dinv + (size_t)N;         // 16N
        float* agg1 = g1 + (size_t)16 * N;      // 16N
        float* g2   = agg1 + (size_t)16 * N;    // 8N
        float* agg2 = g2 + (size_t)8 * N;       // 8N

        hipMemsetAsync(dinv, 0, (size_t)N * 4, stream);
        hipMemsetAsync(agg1, 0, (size_t)16 * N * 4, stream);
        hipMemsetAsync(agg2, 0, (size_t)8 * N * 4, stream);

        k_count<<<(E + BLK - 1) / BLK, BLK, 0, stream>>>(dst, E, N, dinv);
        k_dinv_f<<<(N + BLK - 1) / BLK, BLK, 0, stream>>>(dinv, N);
        k_transform1<<<(N + BLK - 1) / BLK, BLK, 0, stream>>>(x, W1, dinv, g1, N);
        {
            size_t tot = (size_t)E * 16;
            k_edge_agg<16><<<(unsigned)((tot + BLK - 1) / BLK), BLK, 0, stream>>>(src, dst, E, N, g1, agg1);
        }
        k_node1<<<(N + BLK - 1) / BLK, BLK, 0, stream>>>(g1, agg1, dinv, b1, W2, g2, N);
        {
            size_t tot = (size_t)E * 8;
            k_edge_agg<8><<<(unsigned)((tot + BLK - 1) / BLK), BLK, 0, stream>>>(src, dst, E, N, g2, agg2);
        }
        k_node2<<<(N + BLK - 1) / BLK, BLK, 0, stream>>>(g2, agg2, dinv, b2, Wfc, bfc, (float*)d_out, N);
    }
}